// Round 6
// baseline (702.491 us; speedup 1.0000x reference)
//
#include <hip/hip_runtime.h>
#include <stdint.h>
#include <stddef.h>

// ---------------------------------------------------------------------------
// Aligner (fp32 I/O): S = ex.eo^T with ex=ix@W^T+b, eo=io@W^T+b;
// out = softmax(S) @ io.   B=8, L=2048, D=1024.
// ALGEBRA: S = x.(W^T W).o^T + rowconst + v2[col] + const; row-constants
// cancel in softmax exactly, v2[m] = (W^T b).o[m] added in scores epilogue.
// M = W^T W precomputed once (split-K, fp32 reduce).  P materialized once
// (bf16) by k_rowsoftmax; PV is a plain bf16 GEMM.
// v2 mainloop (256x256, 2-slot ring, vmcnt(8)) for gproj/gscores/pvg —
// all at 1 block/CU, MFMA-roofline schedule.  v1 (256x128) kept for wtw.
// XCD remap on gscores only; gproj/pvg natural maps already group
// A-panel-sharing blocks per XCD.
// ---------------------------------------------------------------------------

typedef short bf16x8 __attribute__((ext_vector_type(8)));   // 8 bf16 (4 VGPRs)
typedef float f32x4  __attribute__((ext_vector_type(4)));   // MFMA 16x16 accum

typedef const __attribute__((address_space(1))) uint32_t* gas_ptr;
typedef __attribute__((address_space(3))) uint32_t* las_ptr;

__device__ __forceinline__ void gl_lds16(const void* g, void* l) {
    __builtin_amdgcn_global_load_lds((gas_ptr)g, (las_ptr)l, 16, 0, 0);
}

__device__ __forceinline__ unsigned short f2bf(float f) {  // RNE
    union { float f; uint32_t u; } v; v.f = f;
    uint32_t r = v.u + 0x7fffu + ((v.u >> 16) & 1u);
    return (unsigned short)(r >> 16);
}
__device__ __forceinline__ float bf2f(unsigned short h) {
    union { uint32_t u; float f; } v; v.u = ((uint32_t)h) << 16; return v.f;
}

#define L_ 2048
#define D_ 1024
#define ROWB 4096          // bytes per interleaved row (2048 bf16)
#define NKT 32             // K-tiles: 2048 cols / 64
#define SLOT 49152         // v1 slot: A[256][64] (32KB) + B[128][64] (16KB)
#define LDSB 32768         // v1 B offset
#define DYN_LDS (3 * SLOT) // v1: 144 KiB ring
#define SLOT2 65536        // v2 slot: A[256][128B] + B[256][128B]
#define LDSB2 32768        // v2 B offset
#define DYN_LDS2 (2 * SLOT2) // v2: 128 KiB ring

// XCD-chunked remap (gscores): XCD k owns a contiguous block range.
__device__ __forceinline__ void xcd_remap(int gx, int gy, int& m, int& n, int& z) {
    const int bid = blockIdx.x + gx * (blockIdx.y + gy * blockIdx.z);
    const int T = gx * gy * (int)gridDim.z;   // divisible by 8
    const int chunk = T >> 3;
    const int b2 = (bid & 7) * chunk + (bid >> 3);
    m = b2 % gx;
    const int r = b2 / gx;
    n = r % gy;
    z = r / gy;
}

// ---------------------------------------------------------------------------
// K-split: fp32 -> hi/lo bf16, interleaved along K in 32-col blocks.
// 8 elems/thread, 16B hi + 16B lo stores.
// ---------------------------------------------------------------------------
__global__ __launch_bounds__(256) void k_split(
        const float* __restrict__ in, unsigned short* __restrict__ hl, int n8) {
    const int i = blockIdx.x * 256 + threadIdx.x;
    if (i >= n8) return;
    const float4* p = (const float4*)in + (size_t)i * 2;
    float4 va = p[0], vb = p[1];
    unsigned short h[8], l[8];
    const float f[8] = {va.x, va.y, va.z, va.w, vb.x, vb.y, vb.z, vb.w};
#pragma unroll
    for (int q = 0; q < 8; q++) {
        h[q] = f2bf(f[q]);
        l[q] = f2bf(f[q] - bf2f(h[q]));
    }
    uint4 hu, lu;
    hu.x = (uint32_t)h[0] | ((uint32_t)h[1] << 16);
    hu.y = (uint32_t)h[2] | ((uint32_t)h[3] << 16);
    hu.z = (uint32_t)h[4] | ((uint32_t)h[5] << 16);
    hu.w = (uint32_t)h[6] | ((uint32_t)h[7] << 16);
    lu.x = (uint32_t)l[0] | ((uint32_t)l[1] << 16);
    lu.y = (uint32_t)l[2] | ((uint32_t)l[3] << 16);
    lu.z = (uint32_t)l[4] | ((uint32_t)l[5] << 16);
    lu.w = (uint32_t)l[6] | ((uint32_t)l[7] << 16);
    const int row = i >> 7;            // D_/8 = 128 chunks per row
    const int c = (i & 127) << 3;      // first real col (multiple of 8)
    const size_t o = (size_t)row * 2048 + ((c >> 5) << 6) + (c & 31);
    *(uint4*)&hl[o]      = hu;
    *(uint4*)&hl[o + 32] = lu;
}

// ---------------------------------------------------------------------------
// K0: Vt[b][n][k] = bf16(V[b][k][n])  (V fp32), LDS-tiled 64x64.
// ---------------------------------------------------------------------------
__global__ __launch_bounds__(256) void k_transpose(
        const float* __restrict__ V, unsigned short* __restrict__ Vt) {
    __shared__ unsigned short tile[64][72];   // +8 pad
    const int b = blockIdx.z, k0 = blockIdx.x * 64, n0 = blockIdx.y * 64;
    const int t = threadIdx.x;
    const int row = t >> 2, cs = (t & 3) * 16;
    const float* src = V + ((size_t)b * L_ + k0 + row) * D_ + n0 + cs;
#pragma unroll
    for (int q = 0; q < 4; q++) {
        float4 f = ((const float4*)src)[q];
        tile[row][cs + q * 4 + 0] = f2bf(f.x);
        tile[row][cs + q * 4 + 1] = f2bf(f.y);
        tile[row][cs + q * 4 + 2] = f2bf(f.z);
        tile[row][cs + q * 4 + 3] = f2bf(f.w);
    }
    __syncthreads();
    union { unsigned short us[16]; uint4 q[2]; } pk;
#pragma unroll
    for (int j = 0; j < 16; j++) pk.us[j] = tile[cs + j][row];
    unsigned short* dst = Vt + ((size_t)b * D_ + n0 + row) * L_ + k0 + cs;
    *(uint4*)dst       = pk.q[0];
    *(uint4*)(dst + 8) = pk.q[1];
}

// ---------------------------------------------------------------------------
// Wt split: Wt[k][interleave(n)] = split(W[n][k]).  Transpose + hi/lo.
// ---------------------------------------------------------------------------
__global__ __launch_bounds__(256) void k_tsplit(
        const float* __restrict__ W, unsigned short* __restrict__ Wt) {
    __shared__ float tile[64][68];   // +4 pad
    const int n0 = blockIdx.x * 64, k0 = blockIdx.y * 64;
    const int t = threadIdx.x;
    const int row = t >> 2, cs = (t & 3) * 16;
    const float* src = W + ((size_t)(n0 + row)) * D_ + k0 + cs;
#pragma unroll
    for (int q = 0; q < 4; q++) {
        float4 f = ((const float4*)src)[q];
        tile[row][cs + q * 4 + 0] = f.x;
        tile[row][cs + q * 4 + 1] = f.y;
        tile[row][cs + q * 4 + 2] = f.z;
        tile[row][cs + q * 4 + 3] = f.w;
    }
    __syncthreads();
    union { unsigned short us[16]; uint4 q[2]; } hi, lo;
#pragma unroll
    for (int j = 0; j < 16; j++) {
        float v = tile[cs + j][row];
        unsigned short h = f2bf(v);
        hi.us[j] = h;
        lo.us[j] = f2bf(v - bf2f(h));
    }
    const int ng = n0 + cs;
    unsigned short* dst = Wt + (size_t)(k0 + row) * 2048 + ((ng >> 5) << 6) + (ng & 31);
    *(uint4*)dst        = hi.q[0];
    *(uint4*)(dst + 8)  = hi.q[1];
    *(uint4*)(dst + 32) = lo.q[0];
    *(uint4*)(dst + 40) = lo.q[1];
}

// ---------------------------------------------------------------------------
// Mainloop v1 (256x128, 3-pass).  Kept for k_wtw (split-K chunks).
// ---------------------------------------------------------------------------
struct Frg { bf16x8 aH[4], aL[4], bH[4], bL[4]; };

__device__ __forceinline__ void mfma48(const Frg& f, f32x4 (&acc)[4][4]) {
    __builtin_amdgcn_s_setprio(1);
#pragma unroll
    for (int i = 0; i < 4; i++)
#pragma unroll
        for (int j = 0; j < 4; j++) {
            f32x4 c = acc[i][j];
            c = __builtin_amdgcn_mfma_f32_16x16x32_bf16(f.aH[i], f.bH[j], c, 0, 0, 0);
            c = __builtin_amdgcn_mfma_f32_16x16x32_bf16(f.aH[i], f.bL[j], c, 0, 0, 0);
            c = __builtin_amdgcn_mfma_f32_16x16x32_bf16(f.aL[i], f.bH[j], c, 0, 0, 0);
            acc[i][j] = c;
        }
    __builtin_amdgcn_s_setprio(0);
}

__device__ __forceinline__ void gemm_mainloop(
        const char* __restrict__ Ag, const char* __restrict__ Bg,
        f32x4 (&acc)[4][4], int kt0, int nkt) {
    extern __shared__ char smem[];
    const int t = threadIdx.x, lane = t & 63, w = t >> 6;
    const int l16 = lane & 15, quad = lane >> 4;
    const int mw = w >> 1, nw = w & 1;
    const int ln8 = lane >> 3, l8 = lane & 7;

    const int scol = (l8 * 16) ^ (ln8 << 4);
    const char* gA = Ag + (size_t)(w * 8 + ln8) * ROWB + scol;
    const char* gB = Bg + (size_t)(w * 8 + ln8) * ROWB + scol;
    const int sdst = w * 1024;

    const int swz  = (l16 & 7) << 4;
    const int colH = (quad * 16) ^ swz;
    const int colL = (64 + quad * 16) ^ swz;
    const int aRow = (mw * 64 + l16) * 128;
    const int bRow = LDSB + (nw * 64 + l16) * 128;

#pragma unroll
    for (int i = 0; i < 4; i++)
#pragma unroll
        for (int j = 0; j < 4; j++) acc[i][j] = (f32x4){0.f, 0.f, 0.f, 0.f};

    auto STAGE = [&](int soff, int ktAbs) {
        char* sb = smem + soff;
        const size_t gko = (size_t)ktAbs * 128;
#pragma unroll
        for (int q = 0; q < 4; q++)
            gl_lds16(gA + (size_t)q * (64 * ROWB) + gko, sb + q * 8192 + sdst);
#pragma unroll
        for (int q = 0; q < 2; q++)
            gl_lds16(gB + (size_t)q * (64 * ROWB) + gko, sb + LDSB + q * 8192 + sdst);
    };
    auto LDF = [&](int soff, Frg& f) {
        const char* cb = smem + soff;
#pragma unroll
        for (int i = 0; i < 4; i++) {
            const int ro = aRow + i * 2048;
            f.aH[i] = *(const bf16x8*)(cb + ro + colH);
            f.aL[i] = *(const bf16x8*)(cb + ro + colL);
        }
#pragma unroll
        for (int j = 0; j < 4; j++) {
            const int ro = bRow + j * 2048;
            f.bH[j] = *(const bf16x8*)(cb + ro + colH);
            f.bL[j] = *(const bf16x8*)(cb + ro + colL);
        }
    };

    STAGE(0, kt0 + 0);
    STAGE(SLOT, kt0 + 1);
    asm volatile("s_waitcnt vmcnt(6)" ::: "memory");
    __builtin_amdgcn_s_barrier();
    Frg fC, fN;
    LDF(0, fC);

    int ktr = 2 & (nkt - 1), sCur = 0;
#pragma unroll 1
    for (int it = 0; it < nkt / 2; ++it) {
        {
            int sStage = sCur + 2 * SLOT; if (sStage >= 3 * SLOT) sStage -= 3 * SLOT;
            int sLd    = sCur + SLOT;     if (sLd    >= 3 * SLOT) sLd    -= 3 * SLOT;
            STAGE(sStage, kt0 + ktr); ktr = (ktr + 1) & (nkt - 1);
            asm volatile("s_waitcnt vmcnt(6)" ::: "memory");
            asm volatile("s_waitcnt lgkmcnt(0)" ::: "memory");
            __builtin_amdgcn_s_barrier();
            LDF(sLd, fN);
            mfma48(fC, acc);
            sCur = sLd;
        }
        {
            int sStage = sCur + 2 * SLOT; if (sStage >= 3 * SLOT) sStage -= 3 * SLOT;
            int sLd    = sCur + SLOT;     if (sLd    >= 3 * SLOT) sLd    -= 3 * SLOT;
            STAGE(sStage, kt0 + ktr); ktr = (ktr + 1) & (nkt - 1);
            asm volatile("s_waitcnt vmcnt(6)" ::: "memory");
            asm volatile("s_waitcnt lgkmcnt(0)" ::: "memory");
            __builtin_amdgcn_s_barrier();
            LDF(sLd, fC);
            mfma48(fN, acc);
            sCur = sLd;
        }
    }
}

// ---------------------------------------------------------------------------
// Mainloop v2 (256x256).  8 waves 2m x 4n, per-wave 128x64, acc[8][4].
// 2-slot 64KB ring, 8 loads/K-tile, vmcnt(8), 2 barriers/K-tile.
// SP3=1: 3-pass hi/lo split (96 MFMA/K-tile); SP3=0: single-pass linear
// K (64 MFMA/K-tile, hh+ll covers both 32-col halves).
// ---------------------------------------------------------------------------
template<int SP3>
__device__ __forceinline__ void gemm_mainloop2(
        const char* __restrict__ Ag, const char* __restrict__ Bg,
        f32x4 (&acc)[8][4]) {
    extern __shared__ char smem[];
    const int t = threadIdx.x, lane = t & 63, w = t >> 6;
    const int l16 = lane & 15, quad = lane >> 4;
    const int mw = w >> 2, nw = w & 3;
    const int ln8 = lane >> 3, l8 = lane & 7;

    const int scol = (l8 * 16) ^ (ln8 << 4);
    const char* gA = Ag + (size_t)(w * 8 + ln8) * ROWB + scol;
    const char* gB = Bg + (size_t)(w * 8 + ln8) * ROWB + scol;
    const int sdst = w * 1024;

    const int swz  = (l16 & 7) << 4;
    const int colH = (quad * 16) ^ swz;
    const int colL = (64 + quad * 16) ^ swz;
    const int aRow = (mw * 128 + l16) * 128;
    const int bRow = LDSB2 + (nw * 64 + l16) * 128;

#pragma unroll
    for (int i = 0; i < 8; i++)
#pragma unroll
        for (int j = 0; j < 4; j++) acc[i][j] = (f32x4){0.f, 0.f, 0.f, 0.f};

    auto STAGE = [&](int soff, int ktAbs) {
        char* sb = smem + soff;
        const size_t gko = (size_t)ktAbs * 128;
#pragma unroll
        for (int q = 0; q < 4; q++)
            gl_lds16(gA + (size_t)q * (64 * ROWB) + gko, sb + q * 8192 + sdst);
#pragma unroll
        for (int q = 0; q < 4; q++)
            gl_lds16(gB + (size_t)q * (64 * ROWB) + gko, sb + LDSB2 + q * 8192 + sdst);
    };
    auto COMPUTE = [&](int soff) {
        const char* cb = smem + soff;
        bf16x8 bH[4], bL[4];
#pragma unroll
        for (int j = 0; j < 4; j++) {
            const int ro = bRow + j * 2048;
            bH[j] = *(const bf16x8*)(cb + ro + colH);
            bL[j] = *(const bf16x8*)(cb + ro + colL);
        }
#pragma unroll
        for (int h = 0; h < 2; h++) {
            bf16x8 aH[4], aL[4];
#pragma unroll
            for (int i = 0; i < 4; i++) {
                const int ro = aRow + h * 8192 + i * 2048;
                aH[i] = *(const bf16x8*)(cb + ro + colH);
                aL[i] = *(const bf16x8*)(cb + ro + colL);
            }
            __builtin_amdgcn_s_setprio(1);
#pragma unroll
            for (int i = 0; i < 4; i++)
#pragma unroll
                for (int j = 0; j < 4; j++) {
                    f32x4 c = acc[h * 4 + i][j];
                    if (SP3) {
                        c = __builtin_amdgcn_mfma_f32_16x16x32_bf16(aH[i], bH[j], c, 0, 0, 0);
                        c = __builtin_amdgcn_mfma_f32_16x16x32_bf16(aH[i], bL[j], c, 0, 0, 0);
                        c = __builtin_amdgcn_mfma_f32_16x16x32_bf16(aL[i], bH[j], c, 0, 0, 0);
                    } else {
                        c = __builtin_amdgcn_mfma_f32_16x16x32_bf16(aH[i], bH[j], c, 0, 0, 0);
                        c = __builtin_amdgcn_mfma_f32_16x16x32_bf16(aL[i], bL[j], c, 0, 0, 0);
                    }
                    acc[h * 4 + i][j] = c;
                }
            __builtin_amdgcn_s_setprio(0);
        }
    };

    STAGE(0, 0);
    int ktn = 1;
#pragma unroll 1
    for (int it = 0; it < NKT / 2; ++it) {
        STAGE(SLOT2, ktn); ktn = (ktn + 1) & (NKT - 1);
        asm volatile("s_waitcnt vmcnt(8)" ::: "memory");
        __builtin_amdgcn_s_barrier();
        COMPUTE(0);
        asm volatile("s_waitcnt lgkmcnt(0)" ::: "memory");
        __builtin_amdgcn_s_barrier();
        STAGE(0, ktn); ktn = (ktn + 1) & (NKT - 1);
        asm volatile("s_waitcnt vmcnt(8)" ::: "memory");
        __builtin_amdgcn_s_barrier();
        COMPUTE(SLOT2);
        asm volatile("s_waitcnt lgkmcnt(0)" ::: "memory");
        __builtin_amdgcn_s_barrier();
    }
}

// ---------------------------------------------------------------------------
// M partials: Mpart[z] = Wt[M0..] @ Wt[N0..]^T over K-chunk z.  (v1)
// ---------------------------------------------------------------------------
__global__ __launch_bounds__(512, 2) void k_wtw(
        const char* __restrict__ Wt, float* __restrict__ Mpart, int nkt) {
    const int M0 = blockIdx.x * 256, N0 = blockIdx.y * 128, z = blockIdx.z;
    f32x4 acc[4][4];
    gemm_mainloop(Wt + (size_t)M0 * ROWB, Wt + (size_t)N0 * ROWB, acc, z * nkt, nkt);

    const int t = threadIdx.x, lane = t & 63, w = t >> 6;
    const int l16 = lane & 15, quad = lane >> 4, mw = w >> 1, nw = w & 1;
    float* Sp = Mpart + ((size_t)z << 20)
              + (size_t)(M0 + mw * 64 + quad * 4) * 1024 + N0 + nw * 64;
#pragma unroll
    for (int i = 0; i < 4; i++)
#pragma unroll
        for (int j = 0; j < 4; j++)
#pragma unroll
            for (int r = 0; r < 4; r++)
                Sp[(size_t)(i * 16 + r) * 1024 + j * 16 + l16] = acc[i][j][r];
}

// ---------------------------------------------------------------------------
// Reduce M partials -> split-interleaved Mhl.
// ---------------------------------------------------------------------------
__global__ __launch_bounds__(256) void k_mreduce(
        const float* __restrict__ Mpart, unsigned short* __restrict__ Mhl, int zn) {
    const int i = blockIdx.x;
    const int j = threadIdx.x * 4;
    float4 s = {0.f, 0.f, 0.f, 0.f};
    for (int z = 0; z < zn; z++) {
        float4 v = *(const float4*)(Mpart + ((size_t)z << 20) + (size_t)i * 1024 + j);
        s.x += v.x; s.y += v.y; s.z += v.z; s.w += v.w;
    }
    unsigned short h0 = f2bf(s.x), h1 = f2bf(s.y), h2 = f2bf(s.z), h3 = f2bf(s.w);
    unsigned short l0 = f2bf(s.x - bf2f(h0)), l1 = f2bf(s.y - bf2f(h1));
    unsigned short l2 = f2bf(s.z - bf2f(h2)), l3 = f2bf(s.w - bf2f(h3));
    uint2 hu, lu;
    hu.x = (uint32_t)h0 | ((uint32_t)h1 << 16);
    hu.y = (uint32_t)h2 | ((uint32_t)h3 << 16);
    lu.x = (uint32_t)l0 | ((uint32_t)l1 << 16);
    lu.y = (uint32_t)l2 | ((uint32_t)l3 << 16);
    const size_t o = (size_t)i * 2048 + ((j >> 5) << 6) + (j & 31);
    *(uint2*)&Mhl[o]      = hu;
    *(uint2*)&Mhl[o + 32] = lu;
}

// ---------------------------------------------------------------------------
// c = W^T b.  Partial slabs + atomicAdd.
// ---------------------------------------------------------------------------
__global__ __launch_bounds__(256) void k_wtb(
        const float* __restrict__ W, const float* __restrict__ b,
        float* __restrict__ c) {
    const int k = blockIdx.x * 256 + threadIdx.x;
    const int n0 = blockIdx.y * 128;
    float s = 0.f;
#pragma unroll 4
    for (int n = 0; n < 128; n++) s += b[n0 + n] * W[(size_t)(n0 + n) * D_ + k];
    atomicAdd(&c[k], s);
}

// ---------------------------------------------------------------------------
// v2[r] = io[r] . c   (per-column softmax bias; exact).  One wave per row.
// ---------------------------------------------------------------------------
__global__ __launch_bounds__(256) void k_v2(
        const float* __restrict__ io, const float* __restrict__ c,
        float* __restrict__ v2) {
    __shared__ float cs[1024];
    const int t = threadIdx.x;
#pragma unroll
    for (int q = 0; q < 4; q++) cs[q * 256 + t] = c[q * 256 + t];
    __syncthreads();
    const int r = blockIdx.x * 4 + (t >> 6);
    const int lane = t & 63;
    const float* row = io + (size_t)r * D_ + lane * 16;
    float s = 0.f;
#pragma unroll
    for (int q = 0; q < 4; q++) {
        float4 v = ((const float4*)row)[q];
        s += v.x * cs[lane * 16 + q * 4 + 0] + v.y * cs[lane * 16 + q * 4 + 1]
           + v.z * cs[lane * 16 + q * 4 + 2] + v.w * cs[lane * 16 + q * 4 + 3];
    }
#pragma unroll
    for (int o = 32; o > 0; o >>= 1) s += __shfl_xor(s, o, 64);
    if (lane == 0) v2[r] = s;
}

// ---------------------------------------------------------------------------
// K1: projection GEMM (v2 256x256, 3-pass).  A = XHL, B = Mhl (symmetric).
// C = x@M -> hi/lo interleaved bf16 store into EHL.
// ---------------------------------------------------------------------------
__global__ __launch_bounds__(512, 2) void k_gproj(
        const char* __restrict__ Ahl, const char* __restrict__ Mhl,
        unsigned short* __restrict__ Ehl) {
    const int M0 = blockIdx.x * 256, N0 = blockIdx.y * 256;
    f32x4 acc[8][4];
    gemm_mainloop2<1>(Ahl + (size_t)M0 * ROWB, Mhl + (size_t)N0 * ROWB, acc);

    const int t = threadIdx.x, lane = t & 63, w = t >> 6;
    const int l16 = lane & 15, quad = lane >> 4, mw = w >> 2, nw = w & 3;
#pragma unroll
    for (int j = 0; j < 4; j++) {
        const int n = N0 + nw * 64 + j * 16 + l16;
        unsigned short* eb = Ehl + (size_t)(M0 + mw * 128 + quad * 4) * 2048
                             + (size_t)(n >> 5) * 64 + (n & 31);
#pragma unroll
        for (int i = 0; i < 8; i++)
#pragma unroll
            for (int r = 0; r < 4; r++) {
                float v = acc[i][j][r];
                unsigned short h  = f2bf(v);
                unsigned short lo = f2bf(v - bf2f(h));
                unsigned short* p = eb + (size_t)(i * 16 + r) * 2048;
                p[0]  = h;
                p[32] = lo;
            }
    }
}

// ---------------------------------------------------------------------------
// K2: S[b] = (xM)[b] @ o[b]^T + v2[col] (v2 mainloop, 3-pass, XCD remap).
// ---------------------------------------------------------------------------
__global__ __launch_bounds__(512, 2) void k_gscores(
        const char* __restrict__ Ehl, const char* __restrict__ Ohl,
        const float* __restrict__ v2, float* __restrict__ S) {
    int mb, nb_, zb;
    xcd_remap(L_ / 256, L_ / 256, mb, nb_, zb);
    const int M0 = mb * 256, N0 = nb_ * 256, bb = zb;
    const char* Ae = Ehl + (size_t)(bb * L_ + M0) * ROWB;
    const char* Be = Ohl + (size_t)(bb * L_ + N0) * ROWB;
    f32x4 acc[8][4];
    gemm_mainloop2<1>(Ae, Be, acc);

    const int t = threadIdx.x, lane = t & 63, w = t >> 6;
    const int l16 = lane & 15, quad = lane >> 4, mw = w >> 2, nw = w & 3;
    float* Sp = S + ((size_t)bb * L_ + M0 + mw * 128 + quad * 4) * (size_t)L_
                  + N0 + nw * 64;
    const float* v2p = v2 + (size_t)bb * L_ + N0 + nw * 64;
#pragma unroll
    for (int j = 0; j < 4; j++) {
        const float vb = v2p[j * 16 + l16];
#pragma unroll
        for (int i = 0; i < 8; i++)
#pragma unroll
            for (int r = 0; r < 4; r++)
                Sp[(size_t)(i * 16 + r) * L_ + j * 16 + l16] = acc[i][j][r] + vb;
    }
}

// ---------------------------------------------------------------------------
// K3: row softmax: P[r] = bf16(exp(S[r]-max)*invSum).
// ---------------------------------------------------------------------------
__global__ __launch_bounds__(256) void k_rowsoftmax(
        const float* __restrict__ S, unsigned short* __restrict__ P) {
    const size_t r = blockIdx.x;
    const float* row = S + r * (size_t)L_;
    const int t = threadIdx.x, lane = t & 63, wave = t >> 6;
    float4 v0 = ((const float4*)row)[t];
    float4 v1 = ((const float4*)row)[t + 256];
    float mx = fmaxf(fmaxf(fmaxf(v0.x, v0.y), fmaxf(v0.z, v0.w)),
                     fmaxf(fmaxf(v1.x, v1.y), fmaxf(v1.z, v1.w)));
#pragma unroll
    for (int o = 32; o > 0; o >>= 1) mx = fmaxf(mx, __shfl_xor(mx, o, 64));
    __shared__ float red[4];
    __shared__ float bmax, binv;
    if (lane == 0) red[wave] = mx;
    __syncthreads();
    if (t == 0) bmax = fmaxf(fmaxf(red[0], red[1]), fmaxf(red[2], red[3]));
    __syncthreads();
    const float m = bmax;
    float e0x = __expf(fminf(v0.x - m, 0.f)), e0y = __expf(fminf(v0.y - m, 0.f));
    float e0z = __expf(fminf(v0.z - m, 0.f)), e0w = __expf(fminf(v0.w - m, 0.f));
    float e1x = __expf(fminf(v1.x - m, 0.f)), e1y = __expf(fminf(v1.y - m, 0.f));
    float e1z = __expf(fminf(v1.z - m, 0.f)), e1w = __expf(fminf(v1.w - m, 0.f));
    float s = e0x + e0y + e0z + e0w + e1x + e1y + e1z + e1w;
#pragma unroll
    for (int o = 32; o > 0; o >>= 1) s += __shfl_xor(s, o, 64);
    __syncthreads();
    if (lane == 0) red[wave] = s;
    __syncthreads();
    if (t == 0) binv = 1.0f / (red[0] + red[1] + red[2] + red[3]);
    __syncthreads();
    const float ril = binv;
    uint2 a, b;
    a.x = (uint32_t)f2bf(e0x * ril) | ((uint32_t)f2bf(e0y * ril) << 16);
    a.y = (uint32_t)f2bf(e0z * ril) | ((uint32_t)f2bf(e0w * ril) << 16);
    b.x = (uint32_t)f2bf(e1x * ril) | ((uint32_t)f2bf(e1y * ril) << 16);
    b.y = (uint32_t)f2bf(e1z * ril) | ((uint32_t)f2bf(e1w * ril) << 16);
    uint2* pr = (uint2*)(P + r * (size_t)L_);
    pr[t]       = a;
    pr[t + 256] = b;
}

// ---------------------------------------------------------------------------
// K4: out[b] = P[b] @ Vt[b]^T (v2 mainloop, single-pass).  Natural bid map
// groups the 4 N-blocks of one (m,z) on a single XCD (n-stride = 8).
// ---------------------------------------------------------------------------
__global__ __launch_bounds__(512, 2) void k_pvg(
        const char* __restrict__ Pbf, const char* __restrict__ Vt,
        float* __restrict__ out) {
    const int M0 = blockIdx.x * 256, N0 = blockIdx.y * 256, bb = blockIdx.z;
    const char* Ae = Pbf + ((size_t)bb * L_ + M0) * ROWB;
    const char* Be = Vt + ((size_t)bb * D_ + N0) * ROWB;
    f32x4 acc[8][4];
    gemm_mainloop2<0>(Ae, Be, acc);

    const int t = threadIdx.x, lane = t & 63, w = t >> 6;
    const int l16 = lane & 15, quad = lane >> 4, mw = w >> 2, nw = w & 3;
    float* op = out + ((size_t)bb * L_ + M0 + mw * 128 + quad * 4) * (size_t)D_
                    + N0 + nw * 64;
#pragma unroll
    for (int i = 0; i < 8; i++)
#pragma unroll
        for (int j = 0; j < 4; j++)
#pragma unroll
            for (int r = 0; r < 4; r++)
                op[(size_t)(i * 16 + r) * D_ + j * 16 + l16] = acc[i][j][r];
}

// ---------------------------------------------------------------------------
extern "C" void kernel_launch(void* const* d_in, const int* in_sizes, int n_in,
                              void* d_out, int out_size, void* d_ws, size_t ws_size,
                              hipStream_t stream) {
    const float* ix   = (const float*)d_in[0];
    const float* io   = (const float*)d_in[1];
    const float* W    = (const float*)d_in[2];
    const float* bias = (const float*)d_in[3];
    float* out = (float*)d_out;

    hipFuncSetAttribute((const void*)k_gproj,
                        hipFuncAttributeMaxDynamicSharedMemorySize, DYN_LDS2);
    hipFuncSetAttribute((const void*)k_gscores,
                        hipFuncAttributeMaxDynamicSharedMemorySize, DYN_LDS2);
    hipFuncSetAttribute((const void*)k_wtw,
                        hipFuncAttributeMaxDynamicSharedMemorySize, DYN_LDS);
    hipFuncSetAttribute((const void*)k_pvg,
                        hipFuncAttributeMaxDynamicSharedMemorySize, DYN_LDS2);

    const size_t MB = 1024 * 1024;
    const size_t PB_EI = (size_t)L_ * ROWB;      // 8 MiB: interleaved split per batch
    const size_t PB_S  = (size_t)L_ * L_ * 4;    // 16 MiB
    const size_t PB_E  = (size_t)L_ * D_ * 2;    // 4 MiB (Vt bf16)
    const size_t PB_ST = (size_t)L_ * 4;         // 8 KiB

    int nb = 8;
    while (nb > 1) {
        size_t need = 4 * MB + (size_t)nb * (2 * PB_EI + PB_S + PB_E + 2 * PB_ST) + 8192;
        if (need <= ws_size) break;
        nb >>= 1;
    }

    char* ws = (char*)d_ws;
    size_t off = 0;
    unsigned short* Mhl = (unsigned short*)(ws + off); off += 4 * MB;
    unsigned short* EHL = (unsigned short*)(ws + off); off += (size_t)nb * PB_EI;
    unsigned short* OHL = (unsigned short*)(ws + off); off += (size_t)nb * PB_EI;
    char* regA = ws + off;                             off += (size_t)nb * PB_S;
    unsigned short* Vt = (unsigned short*)(ws + off);  off += (size_t)nb * PB_E;
    float* v2   = (float*)(ws + off);                  off += (size_t)nb * PB_ST;
    float* cvec = (float*)(ws + off);                  off += 4096;
    unsigned short* WtHL = EHL;
    float* Mpart = (float*)OHL;
    unsigned short* Pbf = EHL;
    const int zsplit = (nb >= 2) ? 8 : 4;
    const int nktc = NKT / zsplit;

    // ---- M = W^T W (once) + c = W^T b ----
    k_tsplit<<<dim3(16, 16), 256, 0, stream>>>(W, WtHL);
    k_wtw<<<dim3(4, 8, zsplit), 512, DYN_LDS, stream>>>((const char*)WtHL, Mpart, nktc);
    k_mreduce<<<1024, 256, 0, stream>>>(Mpart, Mhl, zsplit);
    hipMemsetAsync(cvec, 0, D_ * sizeof(float), stream);
    k_wtb<<<dim3(4, 8), 256, 0, stream>>>(W, bias, cvec);

    for (int b0 = 0; b0 < 8; b0 += nb) {
        const float* ixc = ix + (size_t)b0 * L_ * D_;
        const float* ioc = io + (size_t)b0 * L_ * D_;
        float* outc = out + (size_t)b0 * L_ * D_;
        const int nLD8 = nb * L_ * D_ / 8;
        const int nbL = nb * L_;
        float* S = (float*)regA;

        k_split<<<nLD8 / 256, 256, 0, stream>>>(ixc, (unsigned short*)regA, nLD8);
        k_split<<<nLD8 / 256, 256, 0, stream>>>(ioc, OHL, nLD8);
        k_transpose<<<dim3(32, 16, nb), 256, 0, stream>>>(ioc, Vt);
        k_v2<<<nbL / 4, 256, 0, stream>>>(ioc, cvec, v2);
        k_gproj<<<dim3(nbL / 256, D_ / 256), 512, DYN_LDS2, stream>>>(
            (const char*)regA, (const char*)Mhl, EHL);
        k_gscores<<<dim3(L_ / 256, L_ / 256, nb), 512, DYN_LDS2, stream>>>(
            (const char*)EHL, (const char*)OHL, v2, S);
        k_rowsoftmax<<<2048 * nb, 256, 0, stream>>>(S, Pbf);
        k_pvg<<<dim3(L_ / 256, D_ / 256, nb), 512, DYN_LDS2, stream>>>(
            (const char*)Pbf, (const char*)Vt, outc);
    }
}

// Round 7
// 701.400 us; speedup vs baseline: 1.0016x; 1.0016x over previous
//
#include <hip/hip_runtime.h>
#include <stdint.h>
#include <stddef.h>

// ---------------------------------------------------------------------------
// Aligner (fp32 I/O): S = ex.eo^T with ex=ix@W^T+b, eo=io@W^T+b;
// out = softmax(S) @ io.   B=8, L=2048, D=1024.
// ALGEBRA: S = x.(W^T W).o^T + rowconst + v2[col] + const; row-constants
// cancel in softmax exactly, v2[m] = (W^T b).o[m] added in scores epilogue.
// M = W^T W precomputed once (split-K, fp32 reduce).  P materialized once
// (bf16) by k_rowsoftmax; PV is a plain bf16 GEMM.
// v2 mainloop (256x256, 2-slot ring, vmcnt(8)) for gproj/gscores/pvg.
// ALL three use the chunked XCD remap: each XCD owns a contiguous block
// range whose lockstep per-K-tile working set (shared B-slice + concurrent
// A subtiles) is L2-resident.  v1 (256x128) kept for wtw.
// ---------------------------------------------------------------------------

typedef short bf16x8 __attribute__((ext_vector_type(8)));   // 8 bf16 (4 VGPRs)
typedef float f32x4  __attribute__((ext_vector_type(4)));   // MFMA 16x16 accum

typedef const __attribute__((address_space(1))) uint32_t* gas_ptr;
typedef __attribute__((address_space(3))) uint32_t* las_ptr;

__device__ __forceinline__ void gl_lds16(const void* g, void* l) {
    __builtin_amdgcn_global_load_lds((gas_ptr)g, (las_ptr)l, 16, 0, 0);
}

__device__ __forceinline__ unsigned short f2bf(float f) {  // RNE
    union { float f; uint32_t u; } v; v.f = f;
    uint32_t r = v.u + 0x7fffu + ((v.u >> 16) & 1u);
    return (unsigned short)(r >> 16);
}
__device__ __forceinline__ float bf2f(unsigned short h) {
    union { uint32_t u; float f; } v; v.u = ((uint32_t)h) << 16; return v.f;
}

#define L_ 2048
#define D_ 1024
#define ROWB 4096          // bytes per interleaved row (2048 bf16)
#define NKT 32             // K-tiles: 2048 cols / 64
#define SLOT 49152         // v1 slot: A[256][64] (32KB) + B[128][64] (16KB)
#define LDSB 32768         // v1 B offset
#define DYN_LDS (3 * SLOT) // v1: 144 KiB ring
#define SLOT2 65536        // v2 slot: A[256][128B] + B[256][128B]
#define LDSB2 32768        // v2 B offset
#define DYN_LDS2 (2 * SLOT2) // v2: 128 KiB ring

// XCD-chunked remap: XCD k (bid%8 under rr dispatch) owns the contiguous
// logical range [k*T/8, (k+1)*T/8).  m is fastest in the logical order, so
// one XCD's concurrent blocks share B-slices and march A-panels in lockstep.
__device__ __forceinline__ void xcd_remap(int gx, int gy, int& m, int& n, int& z) {
    const int bid = blockIdx.x + gx * (blockIdx.y + gy * blockIdx.z);
    const int T = gx * gy * (int)gridDim.z;   // divisible by 8 in all configs
    const int chunk = T >> 3;
    const int b2 = (bid & 7) * chunk + (bid >> 3);
    m = b2 % gx;
    const int r = b2 / gx;
    n = r % gy;
    z = r / gy;
}

// ---------------------------------------------------------------------------
// K-split: fp32 -> hi/lo bf16, interleaved along K in 32-col blocks.
// ---------------------------------------------------------------------------
__global__ __launch_bounds__(256) void k_split(
        const float* __restrict__ in, unsigned short* __restrict__ hl, int n4) {
    const int i = blockIdx.x * 256 + threadIdx.x;
    if (i >= n4) return;
    float4 v = ((const float4*)in)[i];
    unsigned short h0 = f2bf(v.x), h1 = f2bf(v.y), h2 = f2bf(v.z), h3 = f2bf(v.w);
    unsigned short l0 = f2bf(v.x - bf2f(h0)), l1 = f2bf(v.y - bf2f(h1));
    unsigned short l2 = f2bf(v.z - bf2f(h2)), l3 = f2bf(v.w - bf2f(h3));
    uint2 hu, lu;
    hu.x = (uint32_t)h0 | ((uint32_t)h1 << 16);
    hu.y = (uint32_t)h2 | ((uint32_t)h3 << 16);
    lu.x = (uint32_t)l0 | ((uint32_t)l1 << 16);
    lu.y = (uint32_t)l2 | ((uint32_t)l3 << 16);
    const int row = i >> 8;
    const int c4 = (i & 255) << 2;
    const size_t o = (size_t)row * 2048 + ((c4 >> 5) << 6) + (c4 & 31);
    *(uint2*)&hl[o]      = hu;
    *(uint2*)&hl[o + 32] = lu;
}

// ---------------------------------------------------------------------------
// K0: Vt[b][n][k] = bf16(V[b][k][n])  (V fp32), LDS-tiled 64x64.
// ---------------------------------------------------------------------------
__global__ __launch_bounds__(256) void k_transpose(
        const float* __restrict__ V, unsigned short* __restrict__ Vt) {
    __shared__ unsigned short tile[64][72];   // +8 pad
    const int b = blockIdx.z, k0 = blockIdx.x * 64, n0 = blockIdx.y * 64;
    const int t = threadIdx.x;
    const int row = t >> 2, cs = (t & 3) * 16;
    const float* src = V + ((size_t)b * L_ + k0 + row) * D_ + n0 + cs;
#pragma unroll
    for (int q = 0; q < 4; q++) {
        float4 f = ((const float4*)src)[q];
        tile[row][cs + q * 4 + 0] = f2bf(f.x);
        tile[row][cs + q * 4 + 1] = f2bf(f.y);
        tile[row][cs + q * 4 + 2] = f2bf(f.z);
        tile[row][cs + q * 4 + 3] = f2bf(f.w);
    }
    __syncthreads();
    union { unsigned short us[16]; uint4 q[2]; } pk;
#pragma unroll
    for (int j = 0; j < 16; j++) pk.us[j] = tile[cs + j][row];
    unsigned short* dst = Vt + ((size_t)b * D_ + n0 + row) * L_ + k0 + cs;
    *(uint4*)dst       = pk.q[0];
    *(uint4*)(dst + 8) = pk.q[1];
}

// ---------------------------------------------------------------------------
// Wt split: Wt[k][interleave(n)] = split(W[n][k]).  Transpose + hi/lo.
// ---------------------------------------------------------------------------
__global__ __launch_bounds__(256) void k_tsplit(
        const float* __restrict__ W, unsigned short* __restrict__ Wt) {
    __shared__ float tile[64][68];   // +4 pad
    const int n0 = blockIdx.x * 64, k0 = blockIdx.y * 64;
    const int t = threadIdx.x;
    const int row = t >> 2, cs = (t & 3) * 16;
    const float* src = W + ((size_t)(n0 + row)) * D_ + k0 + cs;
#pragma unroll
    for (int q = 0; q < 4; q++) {
        float4 f = ((const float4*)src)[q];
        tile[row][cs + q * 4 + 0] = f.x;
        tile[row][cs + q * 4 + 1] = f.y;
        tile[row][cs + q * 4 + 2] = f.z;
        tile[row][cs + q * 4 + 3] = f.w;
    }
    __syncthreads();
    union { unsigned short us[16]; uint4 q[2]; } hi, lo;
#pragma unroll
    for (int j = 0; j < 16; j++) {
        float v = tile[cs + j][row];
        unsigned short h = f2bf(v);
        hi.us[j] = h;
        lo.us[j] = f2bf(v - bf2f(h));
    }
    const int ng = n0 + cs;
    unsigned short* dst = Wt + (size_t)(k0 + row) * 2048 + ((ng >> 5) << 6) + (ng & 31);
    *(uint4*)dst        = hi.q[0];
    *(uint4*)(dst + 8)  = hi.q[1];
    *(uint4*)(dst + 32) = lo.q[0];
    *(uint4*)(dst + 40) = lo.q[1];
}

// ---------------------------------------------------------------------------
// Mainloop v1 (256x128, 3-pass).  Kept for k_wtw (split-K chunks).
// ---------------------------------------------------------------------------
struct Frg { bf16x8 aH[4], aL[4], bH[4], bL[4]; };

__device__ __forceinline__ void mfma48(const Frg& f, f32x4 (&acc)[4][4]) {
    __builtin_amdgcn_s_setprio(1);
#pragma unroll
    for (int i = 0; i < 4; i++)
#pragma unroll
        for (int j = 0; j < 4; j++) {
            f32x4 c = acc[i][j];
            c = __builtin_amdgcn_mfma_f32_16x16x32_bf16(f.aH[i], f.bH[j], c, 0, 0, 0);
            c = __builtin_amdgcn_mfma_f32_16x16x32_bf16(f.aH[i], f.bL[j], c, 0, 0, 0);
            c = __builtin_amdgcn_mfma_f32_16x16x32_bf16(f.aL[i], f.bH[j], c, 0, 0, 0);
            acc[i][j] = c;
        }
    __builtin_amdgcn_s_setprio(0);
}

__device__ __forceinline__ void gemm_mainloop(
        const char* __restrict__ Ag, const char* __restrict__ Bg,
        f32x4 (&acc)[4][4], int kt0, int nkt) {
    extern __shared__ char smem[];
    const int t = threadIdx.x, lane = t & 63, w = t >> 6;
    const int l16 = lane & 15, quad = lane >> 4;
    const int mw = w >> 1, nw = w & 1;
    const int ln8 = lane >> 3, l8 = lane & 7;

    const int scol = (l8 * 16) ^ (ln8 << 4);
    const char* gA = Ag + (size_t)(w * 8 + ln8) * ROWB + scol;
    const char* gB = Bg + (size_t)(w * 8 + ln8) * ROWB + scol;
    const int sdst = w * 1024;

    const int swz  = (l16 & 7) << 4;
    const int colH = (quad * 16) ^ swz;
    const int colL = (64 + quad * 16) ^ swz;
    const int aRow = (mw * 64 + l16) * 128;
    const int bRow = LDSB + (nw * 64 + l16) * 128;

#pragma unroll
    for (int i = 0; i < 4; i++)
#pragma unroll
        for (int j = 0; j < 4; j++) acc[i][j] = (f32x4){0.f, 0.f, 0.f, 0.f};

    auto STAGE = [&](int soff, int ktAbs) {
        char* sb = smem + soff;
        const size_t gko = (size_t)ktAbs * 128;
#pragma unroll
        for (int q = 0; q < 4; q++)
            gl_lds16(gA + (size_t)q * (64 * ROWB) + gko, sb + q * 8192 + sdst);
#pragma unroll
        for (int q = 0; q < 2; q++)
            gl_lds16(gB + (size_t)q * (64 * ROWB) + gko, sb + LDSB + q * 8192 + sdst);
    };
    auto LDF = [&](int soff, Frg& f) {
        const char* cb = smem + soff;
#pragma unroll
        for (int i = 0; i < 4; i++) {
            const int ro = aRow + i * 2048;
            f.aH[i] = *(const bf16x8*)(cb + ro + colH);
            f.aL[i] = *(const bf16x8*)(cb + ro + colL);
        }
#pragma unroll
        for (int j = 0; j < 4; j++) {
            const int ro = bRow + j * 2048;
            f.bH[j] = *(const bf16x8*)(cb + ro + colH);
            f.bL[j] = *(const bf16x8*)(cb + ro + colL);
        }
    };

    STAGE(0, kt0 + 0);
    STAGE(SLOT, kt0 + 1);
    asm volatile("s_waitcnt vmcnt(6)" ::: "memory");
    __builtin_amdgcn_s_barrier();
    Frg fC, fN;
    LDF(0, fC);

    int ktr = 2 & (nkt - 1), sCur = 0;
#pragma unroll 1
    for (int it = 0; it < nkt / 2; ++it) {
        {
            int sStage = sCur + 2 * SLOT; if (sStage >= 3 * SLOT) sStage -= 3 * SLOT;
            int sLd    = sCur + SLOT;     if (sLd    >= 3 * SLOT) sLd    -= 3 * SLOT;
            STAGE(sStage, kt0 + ktr); ktr = (ktr + 1) & (nkt - 1);
            asm volatile("s_waitcnt vmcnt(6)" ::: "memory");
            asm volatile("s_waitcnt lgkmcnt(0)" ::: "memory");
            __builtin_amdgcn_s_barrier();
            LDF(sLd, fN);
            mfma48(fC, acc);
            sCur = sLd;
        }
        {
            int sStage = sCur + 2 * SLOT; if (sStage >= 3 * SLOT) sStage -= 3 * SLOT;
            int sLd    = sCur + SLOT;     if (sLd    >= 3 * SLOT) sLd    -= 3 * SLOT;
            STAGE(sStage, kt0 + ktr); ktr = (ktr + 1) & (nkt - 1);
            asm volatile("s_waitcnt vmcnt(6)" ::: "memory");
            asm volatile("s_waitcnt lgkmcnt(0)" ::: "memory");
            __builtin_amdgcn_s_barrier();
            LDF(sLd, fC);
            mfma48(fN, acc);
            sCur = sLd;
        }
    }
}

// ---------------------------------------------------------------------------
// Mainloop v2 (256x256).  8 waves 2m x 4n, per-wave 128x64, acc[8][4].
// 2-slot 64KB ring, 8 loads/K-tile, vmcnt(8), 2 barriers/K-tile.
// SP3=1: 3-pass hi/lo split (96 MFMA/K-tile); SP3=0: single-pass linear K.
// ---------------------------------------------------------------------------
template<int SP3>
__device__ __forceinline__ void gemm_mainloop2(
        const char* __restrict__ Ag, const char* __restrict__ Bg,
        f32x4 (&acc)[8][4]) {
    extern __shared__ char smem[];
    const int t = threadIdx.x, lane = t & 63, w = t >> 6;
    const int l16 = lane & 15, quad = lane >> 4;
    const int mw = w >> 2, nw = w & 3;
    const int ln8 = lane >> 3, l8 = lane & 7;

    const int scol = (l8 * 16) ^ (ln8 << 4);
    const char* gA = Ag + (size_t)(w * 8 + ln8) * ROWB + scol;
    const char* gB = Bg + (size_t)(w * 8 + ln8) * ROWB + scol;
    const int sdst = w * 1024;

    const int swz  = (l16 & 7) << 4;
    const int colH = (quad * 16) ^ swz;
    const int colL = (64 + quad * 16) ^ swz;
    const int aRow = (mw * 128 + l16) * 128;
    const int bRow = LDSB2 + (nw * 64 + l16) * 128;

#pragma unroll
    for (int i = 0; i < 8; i++)
#pragma unroll
        for (int j = 0; j < 4; j++) acc[i][j] = (f32x4){0.f, 0.f, 0.f, 0.f};

    auto STAGE = [&](int soff, int ktAbs) {
        char* sb = smem + soff;
        const size_t gko = (size_t)ktAbs * 128;
#pragma unroll
        for (int q = 0; q < 4; q++)
            gl_lds16(gA + (size_t)q * (64 * ROWB) + gko, sb + q * 8192 + sdst);
#pragma unroll
        for (int q = 0; q < 4; q++)
            gl_lds16(gB + (size_t)q * (64 * ROWB) + gko, sb + LDSB2 + q * 8192 + sdst);
    };
    auto COMPUTE = [&](int soff) {
        const char* cb = smem + soff;
        bf16x8 bH[4], bL[4];
#pragma unroll
        for (int j = 0; j < 4; j++) {
            const int ro = bRow + j * 2048;
            bH[j] = *(const bf16x8*)(cb + ro + colH);
            bL[j] = *(const bf16x8*)(cb + ro + colL);
        }
#pragma unroll
        for (int h = 0; h < 2; h++) {
            bf16x8 aH[4], aL[4];
#pragma unroll
            for (int i = 0; i < 4; i++) {
                const int ro = aRow + h * 8192 + i * 2048;
                aH[i] = *(const bf16x8*)(cb + ro + colH);
                aL[i] = *(const bf16x8*)(cb + ro + colL);
            }
            __builtin_amdgcn_s_setprio(1);
#pragma unroll
            for (int i = 0; i < 4; i++)
#pragma unroll
                for (int j = 0; j < 4; j++) {
                    f32x4 c = acc[h * 4 + i][j];
                    if (SP3) {
                        c = __builtin_amdgcn_mfma_f32_16x16x32_bf16(aH[i], bH[j], c, 0, 0, 0);
                        c = __builtin_amdgcn_mfma_f32_16x16x32_bf16(aH[i], bL[j], c, 0, 0, 0);
                        c = __builtin_amdgcn_mfma_f32_16x16x32_bf16(aL[i], bH[j], c, 0, 0, 0);
                    } else {
                        c = __builtin_amdgcn_mfma_f32_16x16x32_bf16(aH[i], bH[j], c, 0, 0, 0);
                        c = __builtin_amdgcn_mfma_f32_16x16x32_bf16(aL[i], bL[j], c, 0, 0, 0);
                    }
                    acc[h * 4 + i][j] = c;
                }
            __builtin_amdgcn_s_setprio(0);
        }
    };

    STAGE(0, 0);
    int ktn = 1;
#pragma unroll 1
    for (int it = 0; it < NKT / 2; ++it) {
        STAGE(SLOT2, ktn); ktn = (ktn + 1) & (NKT - 1);
        asm volatile("s_waitcnt vmcnt(8)" ::: "memory");
        __builtin_amdgcn_s_barrier();
        COMPUTE(0);
        asm volatile("s_waitcnt lgkmcnt(0)" ::: "memory");
        __builtin_amdgcn_s_barrier();
        STAGE(0, ktn); ktn = (ktn + 1) & (NKT - 1);
        asm volatile("s_waitcnt vmcnt(8)" ::: "memory");
        __builtin_amdgcn_s_barrier();
        COMPUTE(SLOT2);
        asm volatile("s_waitcnt lgkmcnt(0)" ::: "memory");
        __builtin_amdgcn_s_barrier();
    }
}

// ---------------------------------------------------------------------------
// M partials: Mpart[z] = Wt[M0..] @ Wt[N0..]^T over K-chunk z.  (v1)
// ---------------------------------------------------------------------------
__global__ __launch_bounds__(512, 2) void k_wtw(
        const char* __restrict__ Wt, float* __restrict__ Mpart, int nkt) {
    const int M0 = blockIdx.x * 256, N0 = blockIdx.y * 128, z = blockIdx.z;
    f32x4 acc[4][4];
    gemm_mainloop(Wt + (size_t)M0 * ROWB, Wt + (size_t)N0 * ROWB, acc, z * nkt, nkt);

    const int t = threadIdx.x, lane = t & 63, w = t >> 6;
    const int l16 = lane & 15, quad = lane >> 4, mw = w >> 1, nw = w & 1;
    float* Sp = Mpart + ((size_t)z << 20)
              + (size_t)(M0 + mw * 64 + quad * 4) * 1024 + N0 + nw * 64;
#pragma unroll
    for (int i = 0; i < 4; i++)
#pragma unroll
        for (int j = 0; j < 4; j++)
#pragma unroll
            for (int r = 0; r < 4; r++)
                Sp[(size_t)(i * 16 + r) * 1024 + j * 16 + l16] = acc[i][j][r];
}

// ---------------------------------------------------------------------------
// Reduce M partials -> split-interleaved Mhl.
// ---------------------------------------------------------------------------
__global__ __launch_bounds__(256) void k_mreduce(
        const float* __restrict__ Mpart, unsigned short* __restrict__ Mhl, int zn) {
    const int i = blockIdx.x;
    const int j = threadIdx.x * 4;
    float4 s = {0.f, 0.f, 0.f, 0.f};
    for (int z = 0; z < zn; z++) {
        float4 v = *(const float4*)(Mpart + ((size_t)z << 20) + (size_t)i * 1024 + j);
        s.x += v.x; s.y += v.y; s.z += v.z; s.w += v.w;
    }
    unsigned short h0 = f2bf(s.x), h1 = f2bf(s.y), h2 = f2bf(s.z), h3 = f2bf(s.w);
    unsigned short l0 = f2bf(s.x - bf2f(h0)), l1 = f2bf(s.y - bf2f(h1));
    unsigned short l2 = f2bf(s.z - bf2f(h2)), l3 = f2bf(s.w - bf2f(h3));
    uint2 hu, lu;
    hu.x = (uint32_t)h0 | ((uint32_t)h1 << 16);
    hu.y = (uint32_t)h2 | ((uint32_t)h3 << 16);
    lu.x = (uint32_t)l0 | ((uint32_t)l1 << 16);
    lu.y = (uint32_t)l2 | ((uint32_t)l3 << 16);
    const size_t o = (size_t)i * 2048 + ((j >> 5) << 6) + (j & 31);
    *(uint2*)&Mhl[o]      = hu;
    *(uint2*)&Mhl[o + 32] = lu;
}

// ---------------------------------------------------------------------------
// c = W^T b.  Partial slabs + atomicAdd.
// ---------------------------------------------------------------------------
__global__ __launch_bounds__(256) void k_wtb(
        const float* __restrict__ W, const float* __restrict__ b,
        float* __restrict__ c) {
    const int k = blockIdx.x * 256 + threadIdx.x;
    const int n0 = blockIdx.y * 128;
    float s = 0.f;
#pragma unroll 4
    for (int n = 0; n < 128; n++) s += b[n0 + n] * W[(size_t)(n0 + n) * D_ + k];
    atomicAdd(&c[k], s);
}

// ---------------------------------------------------------------------------
// v2[r] = io[r] . c   (per-column softmax bias; exact).  One wave per row.
// ---------------------------------------------------------------------------
__global__ __launch_bounds__(256) void k_v2(
        const float* __restrict__ io, const float* __restrict__ c,
        float* __restrict__ v2) {
    __shared__ float cs[1024];
    const int t = threadIdx.x;
#pragma unroll
    for (int q = 0; q < 4; q++) cs[q * 256 + t] = c[q * 256 + t];
    __syncthreads();
    const int r = blockIdx.x * 4 + (t >> 6);
    const int lane = t & 63;
    const float* row = io + (size_t)r * D_ + lane * 16;
    float s = 0.f;
#pragma unroll
    for (int q = 0; q < 4; q++) {
        float4 v = ((const float4*)row)[q];
        s += v.x * cs[lane * 16 + q * 4 + 0] + v.y * cs[lane * 16 + q * 4 + 1]
           + v.z * cs[lane * 16 + q * 4 + 2] + v.w * cs[lane * 16 + q * 4 + 3];
    }
#pragma unroll
    for (int o = 32; o > 0; o >>= 1) s += __shfl_xor(s, o, 64);
    if (lane == 0) v2[r] = s;
}

// ---------------------------------------------------------------------------
// K1: projection GEMM (v2 256x256, 3-pass, chunked XCD remap).
// A = XHL, B = Mhl (symmetric).  C = x@M -> hi/lo interleaved into EHL.
// ---------------------------------------------------------------------------
__global__ __launch_bounds__(512, 2) void k_gproj(
        const char* __restrict__ Ahl, const char* __restrict__ Mhl,
        unsigned short* __restrict__ Ehl) {
    int mb, nb_, zb;
    xcd_remap(gridDim.x, gridDim.y, mb, nb_, zb);
    const int M0 = mb * 256, N0 = nb_ * 256;
    f32x4 acc[8][4];
    gemm_mainloop2<1>(Ahl + (size_t)M0 * ROWB, Mhl + (size_t)N0 * ROWB, acc);

    const int t = threadIdx.x, lane = t & 63, w = t >> 6;
    const int l16 = lane & 15, quad = lane >> 4, mw = w >> 2, nw = w & 3;
#pragma unroll
    for (int j = 0; j < 4; j++) {
        const int n = N0 + nw * 64 + j * 16 + l16;
        unsigned short* eb = Ehl + (size_t)(M0 + mw * 128 + quad * 4) * 2048
                             + (size_t)(n >> 5) * 64 + (n & 31);
#pragma unroll
        for (int i = 0; i < 8; i++)
#pragma unroll
            for (int r = 0; r < 4; r++) {
                float v = acc[i][j][r];
                unsigned short h  = f2bf(v);
                unsigned short lo = f2bf(v - bf2f(h));
                unsigned short* p = eb + (size_t)(i * 16 + r) * 2048;
                p[0]  = h;
                p[32] = lo;
            }
    }
}

// ---------------------------------------------------------------------------
// K2: S[b] = (xM)[b] @ o[b]^T + v2[col] (v2 mainloop, 3-pass, XCD remap).
// ---------------------------------------------------------------------------
__global__ __launch_bounds__(512, 2) void k_gscores(
        const char* __restrict__ Ehl, const char* __restrict__ Ohl,
        const float* __restrict__ v2, float* __restrict__ S) {
    int mb, nb_, zb;
    xcd_remap(L_ / 256, L_ / 256, mb, nb_, zb);
    const int M0 = mb * 256, N0 = nb_ * 256, bb = zb;
    const char* Ae = Ehl + (size_t)(bb * L_ + M0) * ROWB;
    const char* Be = Ohl + (size_t)(bb * L_ + N0) * ROWB;
    f32x4 acc[8][4];
    gemm_mainloop2<1>(Ae, Be, acc);

    const int t = threadIdx.x, lane = t & 63, w = t >> 6;
    const int l16 = lane & 15, quad = lane >> 4, mw = w >> 2, nw = w & 3;
    float* Sp = S + ((size_t)bb * L_ + M0 + mw * 128 + quad * 4) * (size_t)L_
                  + N0 + nw * 64;
    const float* v2p = v2 + (size_t)bb * L_ + N0 + nw * 64;
#pragma unroll
    for (int j = 0; j < 4; j++) {
        const float vb = v2p[j * 16 + l16];
#pragma unroll
        for (int i = 0; i < 8; i++)
#pragma unroll
            for (int r = 0; r < 4; r++)
                Sp[(size_t)(i * 16 + r) * L_ + j * 16 + l16] = acc[i][j][r] + vb;
    }
}

// ---------------------------------------------------------------------------
// K3: row softmax: P[r] = bf16(exp(S[r]-max)*invSum).
// ---------------------------------------------------------------------------
__global__ __launch_bounds__(256) void k_rowsoftmax(
        const float* __restrict__ S, unsigned short* __restrict__ P) {
    const size_t r = blockIdx.x;
    const float* row = S + r * (size_t)L_;
    const int t = threadIdx.x, lane = t & 63, wave = t >> 6;
    float4 v0 = ((const float4*)row)[t];
    float4 v1 = ((const float4*)row)[t + 256];
    float mx = fmaxf(fmaxf(fmaxf(v0.x, v0.y), fmaxf(v0.z, v0.w)),
                     fmaxf(fmaxf(v1.x, v1.y), fmaxf(v1.z, v1.w)));
#pragma unroll
    for (int o = 32; o > 0; o >>= 1) mx = fmaxf(mx, __shfl_xor(mx, o, 64));
    __shared__ float red[4];
    __shared__ float bmax, binv;
    if (lane == 0) red[wave] = mx;
    __syncthreads();
    if (t == 0) bmax = fmaxf(fmaxf(red[0], red[1]), fmaxf(red[2], red[3]));
    __syncthreads();
    const float m = bmax;
    float e0x = __expf(fminf(v0.x - m, 0.f)), e0y = __expf(fminf(v0.y - m, 0.f));
    float e0z = __expf(fminf(v0.z - m, 0.f)), e0w = __expf(fminf(v0.w - m, 0.f));
    float e1x = __expf(fminf(v1.x - m, 0.f)), e1y = __expf(fminf(v1.y - m, 0.f));
    float e1z = __expf(fminf(v1.z - m, 0.f)), e1w = __expf(fminf(v1.w - m, 0.f));
    float s = e0x + e0y + e0z + e0w + e1x + e1y + e1z + e1w;
#pragma unroll
    for (int o = 32; o > 0; o >>= 1) s += __shfl_xor(s, o, 64);
    __syncthreads();
    if (lane == 0) red[wave] = s;
    __syncthreads();
    if (t == 0) binv = 1.0f / (red[0] + red[1] + red[2] + red[3]);
    __syncthreads();
    const float ril = binv;
    uint2 a, b;
    a.x = (uint32_t)f2bf(e0x * ril) | ((uint32_t)f2bf(e0y * ril) << 16);
    a.y = (uint32_t)f2bf(e0z * ril) | ((uint32_t)f2bf(e0w * ril) << 16);
    b.x = (uint32_t)f2bf(e1x * ril) | ((uint32_t)f2bf(e1y * ril) << 16);
    b.y = (uint32_t)f2bf(e1z * ril) | ((uint32_t)f2bf(e1w * ril) << 16);
    uint2* pr = (uint2*)(P + r * (size_t)L_);
    pr[t]       = a;
    pr[t + 256] = b;
}

// ---------------------------------------------------------------------------
// K4: out[b] = P[b] @ Vt[b]^T (v2 single-pass, chunked XCD remap: XCD k
// owns batch k -> Vt[k] (4 MiB) is L2-resident, P streams in lockstep).
// ---------------------------------------------------------------------------
__global__ __launch_bounds__(512, 2) void k_pvg(
        const char* __restrict__ Pbf, const char* __restrict__ Vt,
        float* __restrict__ out) {
    int mb, nb_, zb;
    xcd_remap(L_ / 256, D_ / 256, mb, nb_, zb);
    const int M0 = mb * 256, N0 = nb_ * 256, bb = zb;
    const char* Ae = Pbf + ((size_t)bb * L_ + M0) * ROWB;
    const char* Be = Vt + ((size_t)bb * D_ + N0) * ROWB;
    f32x4 acc[8][4];
    gemm_mainloop2<0>(Ae, Be, acc);

    const int t = threadIdx.x, lane = t & 63, w = t >> 6;
    const int l16 = lane & 15, quad = lane >> 4, mw = w >> 2, nw = w & 3;
    float* op = out + ((size_t)bb * L_ + M0 + mw * 128 + quad * 4) * (size_t)D_
                    + N0 + nw * 64;
#pragma unroll
    for (int i = 0; i < 8; i++)
#pragma unroll
        for (int j = 0; j < 4; j++)
#pragma unroll
            for (int r = 0; r < 4; r++)
                op[(size_t)(i * 16 + r) * D_ + j * 16 + l16] = acc[i][j][r];
}

// ---------------------------------------------------------------------------
extern "C" void kernel_launch(void* const* d_in, const int* in_sizes, int n_in,
                              void* d_out, int out_size, void* d_ws, size_t ws_size,
                              hipStream_t stream) {
    const float* ix   = (const float*)d_in[0];
    const float* io   = (const float*)d_in[1];
    const float* W    = (const float*)d_in[2];
    const float* bias = (const float*)d_in[3];
    float* out = (float*)d_out;

    hipFuncSetAttribute((const void*)k_gproj,
                        hipFuncAttributeMaxDynamicSharedMemorySize, DYN_LDS2);
    hipFuncSetAttribute((const void*)k_gscores,
                        hipFuncAttributeMaxDynamicSharedMemorySize, DYN_LDS2);
    hipFuncSetAttribute((const void*)k_wtw,
                        hipFuncAttributeMaxDynamicSharedMemorySize, DYN_LDS);
    hipFuncSetAttribute((const void*)k_pvg,
                        hipFuncAttributeMaxDynamicSharedMemorySize, DYN_LDS2);

    const size_t MB = 1024 * 1024;
    const size_t PB_EI = (size_t)L_ * ROWB;      // 8 MiB: interleaved split per batch
    const size_t PB_S  = (size_t)L_ * L_ * 4;    // 16 MiB
    const size_t PB_E  = (size_t)L_ * D_ * 2;    // 4 MiB (Vt bf16)
    const size_t PB_ST = (size_t)L_ * 4;         // 8 KiB

    int nb = 8;
    while (nb > 1) {
        size_t need = 4 * MB + (size_t)nb * (2 * PB_EI + PB_S + PB_E + 2 * PB_ST) + 8192;
        if (need <= ws_size) break;
        nb >>= 1;
    }

    char* ws = (char*)d_ws;
    size_t off = 0;
    unsigned short* Mhl = (unsigned short*)(ws + off); off += 4 * MB;
    unsigned short* EHL = (unsigned short*)(ws + off); off += (size_t)nb * PB_EI;
    unsigned short* OHL = (unsigned short*)(ws + off); off += (size_t)nb * PB_EI;
    char* regA = ws + off;                             off += (size_t)nb * PB_S;
    unsigned short* Vt = (unsigned short*)(ws + off);  off += (size_t)nb * PB_E;
    float* v2   = (float*)(ws + off);                  off += (size_t)nb * PB_ST;
    float* cvec = (float*)(ws + off);                  off += 4096;
    unsigned short* WtHL = EHL;
    float* Mpart = (float*)OHL;
    unsigned short* Pbf = EHL;
    const int zsplit = (nb >= 2) ? 8 : 4;
    const int nktc = NKT / zsplit;

    // ---- M = W^T W (once) + c = W^T b ----
    k_tsplit<<<dim3(16, 16), 256, 0, stream>>>(W, WtHL);
    k_wtw<<<dim3(4, 8, zsplit), 512, DYN_LDS, stream>>>((const char*)WtHL, Mpart, nktc);
    k_mreduce<<<1024, 256, 0, stream>>>(Mpart, Mhl, zsplit);
    hipMemsetAsync(cvec, 0, D_ * sizeof(float), stream);
    k_wtb<<<dim3(4, 8), 256, 0, stream>>>(W, bias, cvec);

    for (int b0 = 0; b0 < 8; b0 += nb) {
        const float* ixc = ix + (size_t)b0 * L_ * D_;
        const float* ioc = io + (size_t)b0 * L_ * D_;
        float* outc = out + (size_t)b0 * L_ * D_;
        const int nLD4 = nb * L_ * D_ / 4;
        const int nbL = nb * L_;
        float* S = (float*)regA;

        k_split<<<nb * 2048, 256, 0, stream>>>(ixc, (unsigned short*)regA, nLD4);
        k_split<<<nb * 2048, 256, 0, stream>>>(ioc, OHL, nLD4);
        k_transpose<<<dim3(32, 16, nb), 256, 0, stream>>>(ioc, Vt);
        k_v2<<<nbL / 4, 256, 0, stream>>>(ioc, cvec, v2);
        k_gproj<<<dim3(nbL / 256, D_ / 256), 512, DYN_LDS2, stream>>>(
            (const char*)regA, (const char*)Mhl, EHL);
        k_gscores<<<dim3(L_ / 256, L_ / 256, nb), 512, DYN_LDS2, stream>>>(
            (const char*)EHL, (const char*)OHL, v2, S);
        k_rowsoftmax<<<2048 * nb, 256, 0, stream>>>(S, Pbf);
        k_pvg<<<dim3(L_ / 256, D_ / 256, nb), 512, DYN_LDS2, stream>>>(
            (const char*)Pbf, (const char*)Vt, outc);
    }
}

// Round 9
// 584.944 us; speedup vs baseline: 1.2010x; 1.1991x over previous
//
#include <hip/hip_runtime.h>
#include <stdint.h>
#include <stddef.h>

// ---------------------------------------------------------------------------
// Aligner (fp32 I/O): S = ex.eo^T with ex=ix@W^T+b, eo=io@W^T+b;
// out = softmax(S) @ io.   B=8, L=2048, D=1024.
// ALGEBRA: S = x.(W^T W).o^T + rowconst + v2[col] + const; row-constants
// cancel in softmax exactly, v2[m] = (W^T b).o[m] added in scores epilogue.
// M = W^T W precomputed once (split-K, fp32 reduce).  P materialized once
// (bf16) by k_rowsoftmax; PV is a plain bf16 GEMM.
// Kernel->mainloop map (nb=4 => every GEMM grid = 256 blocks = 1/CU):
//   gproj: v1 256x128 3-pass, natural map, grid (32,8)
//   gscores: v2 256x256 3-pass, XCD remap, grid (8,8,nb)
//   pvg: v1 256x128 single-pass, XCD remap, grid (8,8,nb)
// MFMA clusters are PASS-OUTERMOST (16 independent MFMAs between acc
// reuses; per-acc accumulation order unchanged -> bit-identical numerics).
// ---------------------------------------------------------------------------

typedef short bf16x8 __attribute__((ext_vector_type(8)));   // 8 bf16 (4 VGPRs)
typedef float f32x4  __attribute__((ext_vector_type(4)));   // MFMA 16x16 accum

typedef const __attribute__((address_space(1))) uint32_t* gas_ptr;
typedef __attribute__((address_space(3))) uint32_t* las_ptr;

__device__ __forceinline__ void gl_lds16(const void* g, void* l) {
    __builtin_amdgcn_global_load_lds((gas_ptr)g, (las_ptr)l, 16, 0, 0);
}

__device__ __forceinline__ unsigned short f2bf(float f) {  // RNE
    union { float f; uint32_t u; } v; v.f = f;
    uint32_t r = v.u + 0x7fffu + ((v.u >> 16) & 1u);
    return (unsigned short)(r >> 16);
}
__device__ __forceinline__ float bf2f(unsigned short h) {
    union { uint32_t u; float f; } v; v.u = ((uint32_t)h) << 16; return v.f;
}

#define L_ 2048
#define D_ 1024
#define ROWB 4096          // bytes per interleaved row (2048 bf16)
#define NKT 32             // K-tiles: 2048 cols / 64
#define SLOT 49152         // v1 slot: A[256][64] (32KB) + B[128][64] (16KB)
#define LDSB 32768         // v1 B offset
#define DYN_LDS (3 * SLOT) // v1: 144 KiB ring
#define SLOT2 65536        // v2 slot: A[256][128B] + B[256][128B]
#define LDSB2 32768        // v2 B offset
#define DYN_LDS2 (2 * SLOT2) // v2: 128 KiB ring

// XCD-chunked remap: XCD k (bid%8 under rr dispatch) owns the contiguous
// logical range [k*T/8, (k+1)*T/8), m fastest.
__device__ __forceinline__ void xcd_remap(int gx, int gy, int& m, int& n, int& z) {
    const int bid = blockIdx.x + gx * (blockIdx.y + gy * blockIdx.z);
    const int T = gx * gy * (int)gridDim.z;   // divisible by 8 in all configs
    const int chunk = T >> 3;
    const int b2 = (bid & 7) * chunk + (bid >> 3);
    m = b2 % gx;
    const int r = b2 / gx;
    n = r % gy;
    z = r / gy;
}

// ---------------------------------------------------------------------------
// K-split: fp32 -> hi/lo bf16, interleaved along K in 32-col blocks.
// ---------------------------------------------------------------------------
__global__ __launch_bounds__(256) void k_split(
        const float* __restrict__ in, unsigned short* __restrict__ hl, int n4) {
    const int i = blockIdx.x * 256 + threadIdx.x;
    if (i >= n4) return;
    float4 v = ((const float4*)in)[i];
    unsigned short h0 = f2bf(v.x), h1 = f2bf(v.y), h2 = f2bf(v.z), h3 = f2bf(v.w);
    unsigned short l0 = f2bf(v.x - bf2f(h0)), l1 = f2bf(v.y - bf2f(h1));
    unsigned short l2 = f2bf(v.z - bf2f(h2)), l3 = f2bf(v.w - bf2f(h3));
    uint2 hu, lu;
    hu.x = (uint32_t)h0 | ((uint32_t)h1 << 16);
    hu.y = (uint32_t)h2 | ((uint32_t)h3 << 16);
    lu.x = (uint32_t)l0 | ((uint32_t)l1 << 16);
    lu.y = (uint32_t)l2 | ((uint32_t)l3 << 16);
    const int row = i >> 8;
    const int c4 = (i & 255) << 2;
    const size_t o = (size_t)row * 2048 + ((c4 >> 5) << 6) + (c4 & 31);
    *(uint2*)&hl[o]      = hu;
    *(uint2*)&hl[o + 32] = lu;
}

// ---------------------------------------------------------------------------
// K0: Vt[b][n][k] = bf16(V[b][k][n])  (V fp32), LDS-tiled 64x64.
// ---------------------------------------------------------------------------
__global__ __launch_bounds__(256) void k_transpose(
        const float* __restrict__ V, unsigned short* __restrict__ Vt) {
    __shared__ unsigned short tile[64][72];   // +8 pad
    const int b = blockIdx.z, k0 = blockIdx.x * 64, n0 = blockIdx.y * 64;
    const int t = threadIdx.x;
    const int row = t >> 2, cs = (t & 3) * 16;
    const float* src = V + ((size_t)b * L_ + k0 + row) * D_ + n0 + cs;
#pragma unroll
    for (int q = 0; q < 4; q++) {
        float4 f = ((const float4*)src)[q];
        tile[row][cs + q * 4 + 0] = f2bf(f.x);
        tile[row][cs + q * 4 + 1] = f2bf(f.y);
        tile[row][cs + q * 4 + 2] = f2bf(f.z);
        tile[row][cs + q * 4 + 3] = f2bf(f.w);
    }
    __syncthreads();
    union { unsigned short us[16]; uint4 q[2]; } pk;
#pragma unroll
    for (int j = 0; j < 16; j++) pk.us[j] = tile[cs + j][row];
    unsigned short* dst = Vt + ((size_t)b * D_ + n0 + row) * L_ + k0 + cs;
    *(uint4*)dst       = pk.q[0];
    *(uint4*)(dst + 8) = pk.q[1];
}

// ---------------------------------------------------------------------------
// Wt split: Wt[k][interleave(n)] = split(W[n][k]).  Transpose + hi/lo.
// ---------------------------------------------------------------------------
__global__ __launch_bounds__(256) void k_tsplit(
        const float* __restrict__ W, unsigned short* __restrict__ Wt) {
    __shared__ float tile[64][68];   // +4 pad
    const int n0 = blockIdx.x * 64, k0 = blockIdx.y * 64;
    const int t = threadIdx.x;
    const int row = t >> 2, cs = (t & 3) * 16;
    const float* src = W + ((size_t)(n0 + row)) * D_ + k0 + cs;
#pragma unroll
    for (int q = 0; q < 4; q++) {
        float4 f = ((const float4*)src)[q];
        tile[row][cs + q * 4 + 0] = f.x;
        tile[row][cs + q * 4 + 1] = f.y;
        tile[row][cs + q * 4 + 2] = f.z;
        tile[row][cs + q * 4 + 3] = f.w;
    }
    __syncthreads();
    union { unsigned short us[16]; uint4 q[2]; } hi, lo;
#pragma unroll
    for (int j = 0; j < 16; j++) {
        float v = tile[cs + j][row];
        unsigned short h = f2bf(v);
        hi.us[j] = h;
        lo.us[j] = f2bf(v - bf2f(h));
    }
    const int ng = n0 + cs;
    unsigned short* dst = Wt + (size_t)(k0 + row) * 2048 + ((ng >> 5) << 6) + (ng & 31);
    *(uint4*)dst        = hi.q[0];
    *(uint4*)(dst + 8)  = hi.q[1];
    *(uint4*)(dst + 32) = lo.q[0];
    *(uint4*)(dst + 40) = lo.q[1];
}

// ---------------------------------------------------------------------------
// Mainloop v1 (256x128).  SP3=1: 3-pass split; SP3=0: single-pass.
// MFMA clusters pass-outermost (independent MFMAs between acc reuses;
// per-acc order HH->HL->LH preserved -> numerics identical).
// ---------------------------------------------------------------------------
struct Frg { bf16x8 aH[4], aL[4], bH[4], bL[4]; };

template<int SP3>
__device__ __forceinline__ void mfma_cluster(const Frg& f, f32x4 (&acc)[4][4]) {
    __builtin_amdgcn_s_setprio(1);
#pragma unroll
    for (int i = 0; i < 4; i++)
#pragma unroll
        for (int j = 0; j < 4; j++)
            acc[i][j] = __builtin_amdgcn_mfma_f32_16x16x32_bf16(f.aH[i], f.bH[j], acc[i][j], 0, 0, 0);
    if (SP3) {
#pragma unroll
        for (int i = 0; i < 4; i++)
#pragma unroll
            for (int j = 0; j < 4; j++)
                acc[i][j] = __builtin_amdgcn_mfma_f32_16x16x32_bf16(f.aH[i], f.bL[j], acc[i][j], 0, 0, 0);
#pragma unroll
        for (int i = 0; i < 4; i++)
#pragma unroll
            for (int j = 0; j < 4; j++)
                acc[i][j] = __builtin_amdgcn_mfma_f32_16x16x32_bf16(f.aL[i], f.bH[j], acc[i][j], 0, 0, 0);
    } else {
#pragma unroll
        for (int i = 0; i < 4; i++)
#pragma unroll
            for (int j = 0; j < 4; j++)
                acc[i][j] = __builtin_amdgcn_mfma_f32_16x16x32_bf16(f.aL[i], f.bL[j], acc[i][j], 0, 0, 0);
    }
    __builtin_amdgcn_s_setprio(0);
}

template<int SP3>
__device__ __forceinline__ void gemm_mainloop(
        const char* __restrict__ Ag, const char* __restrict__ Bg,
        f32x4 (&acc)[4][4], int kt0, int nkt) {
    extern __shared__ char smem[];
    const int t = threadIdx.x, lane = t & 63, w = t >> 6;
    const int l16 = lane & 15, quad = lane >> 4;
    const int mw = w >> 1, nw = w & 1;
    const int ln8 = lane >> 3, l8 = lane & 7;

    const int scol = (l8 * 16) ^ (ln8 << 4);
    const char* gA = Ag + (size_t)(w * 8 + ln8) * ROWB + scol;
    const char* gB = Bg + (size_t)(w * 8 + ln8) * ROWB + scol;
    const int sdst = w * 1024;

    const int swz  = (l16 & 7) << 4;
    const int colH = (quad * 16) ^ swz;
    const int colL = (64 + quad * 16) ^ swz;
    const int aRow = (mw * 64 + l16) * 128;
    const int bRow = LDSB + (nw * 64 + l16) * 128;

#pragma unroll
    for (int i = 0; i < 4; i++)
#pragma unroll
        for (int j = 0; j < 4; j++) acc[i][j] = (f32x4){0.f, 0.f, 0.f, 0.f};

    auto STAGE = [&](int soff, int ktAbs) {
        char* sb = smem + soff;
        const size_t gko = (size_t)ktAbs * 128;
#pragma unroll
        for (int q = 0; q < 4; q++)
            gl_lds16(gA + (size_t)q * (64 * ROWB) + gko, sb + q * 8192 + sdst);
#pragma unroll
        for (int q = 0; q < 2; q++)
            gl_lds16(gB + (size_t)q * (64 * ROWB) + gko, sb + LDSB + q * 8192 + sdst);
    };
    auto LDF = [&](int soff, Frg& f) {
        const char* cb = smem + soff;
#pragma unroll
        for (int i = 0; i < 4; i++) {
            const int ro = aRow + i * 2048;
            f.aH[i] = *(const bf16x8*)(cb + ro + colH);
            f.aL[i] = *(const bf16x8*)(cb + ro + colL);
        }
#pragma unroll
        for (int j = 0; j < 4; j++) {
            const int ro = bRow + j * 2048;
            f.bH[j] = *(const bf16x8*)(cb + ro + colH);
            f.bL[j] = *(const bf16x8*)(cb + ro + colL);
        }
    };

    STAGE(0, kt0 + 0);
    STAGE(SLOT, kt0 + 1);
    asm volatile("s_waitcnt vmcnt(6)" ::: "memory");
    __builtin_amdgcn_s_barrier();
    Frg fC, fN;
    LDF(0, fC);

    int ktr = 2 & (nkt - 1), sCur = 0;
#pragma unroll 1
    for (int it = 0; it < nkt / 2; ++it) {
        {
            int sStage = sCur + 2 * SLOT; if (sStage >= 3 * SLOT) sStage -= 3 * SLOT;
            int sLd    = sCur + SLOT;     if (sLd    >= 3 * SLOT) sLd    -= 3 * SLOT;
            STAGE(sStage, kt0 + ktr); ktr = (ktr + 1) & (nkt - 1);
            asm volatile("s_waitcnt vmcnt(6)" ::: "memory");
            asm volatile("s_waitcnt lgkmcnt(0)" ::: "memory");
            __builtin_amdgcn_s_barrier();
            LDF(sLd, fN);
            mfma_cluster<SP3>(fC, acc);
            sCur = sLd;
        }
        {
            int sStage = sCur + 2 * SLOT; if (sStage >= 3 * SLOT) sStage -= 3 * SLOT;
            int sLd    = sCur + SLOT;     if (sLd    >= 3 * SLOT) sLd    -= 3 * SLOT;
            STAGE(sStage, kt0 + ktr); ktr = (ktr + 1) & (nkt - 1);
            asm volatile("s_waitcnt vmcnt(6)" ::: "memory");
            asm volatile("s_waitcnt lgkmcnt(0)" ::: "memory");
            __builtin_amdgcn_s_barrier();
            LDF(sLd, fC);
            mfma_cluster<SP3>(fN, acc);
            sCur = sLd;
        }
    }
}

// ---------------------------------------------------------------------------
// Mainloop v2 (256x256, 3-pass).  8 waves 2m x 4n, per-wave 128x64,
// acc[8][4].  2-slot 64KB ring, vmcnt(8), 2 barriers/K-tile.
// COMPUTE pass-outermost per h-half (numerics identical).
// ---------------------------------------------------------------------------
__device__ __forceinline__ void gemm_mainloop2(
        const char* __restrict__ Ag, const char* __restrict__ Bg,
        f32x4 (&acc)[8][4]) {
    extern __shared__ char smem[];
    const int t = threadIdx.x, lane = t & 63, w = t >> 6;
    const int l16 = lane & 15, quad = lane >> 4;
    const int mw = w >> 2, nw = w & 3;
    const int ln8 = lane >> 3, l8 = lane & 7;

    const int scol = (l8 * 16) ^ (ln8 << 4);
    const char* gA = Ag + (size_t)(w * 8 + ln8) * ROWB + scol;
    const char* gB = Bg + (size_t)(w * 8 + ln8) * ROWB + scol;
    const int sdst = w * 1024;

    const int swz  = (l16 & 7) << 4;
    const int colH = (quad * 16) ^ swz;
    const int colL = (64 + quad * 16) ^ swz;
    const int aRow = (mw * 128 + l16) * 128;
    const int bRow = LDSB2 + (nw * 64 + l16) * 128;

#pragma unroll
    for (int i = 0; i < 8; i++)
#pragma unroll
        for (int j = 0; j < 4; j++) acc[i][j] = (f32x4){0.f, 0.f, 0.f, 0.f};

    auto STAGE = [&](int soff, int ktAbs) {
        char* sb = smem + soff;
        const size_t gko = (size_t)ktAbs * 128;
#pragma unroll
        for (int q = 0; q < 4; q++)
            gl_lds16(gA + (size_t)q * (64 * ROWB) + gko, sb + q * 8192 + sdst);
#pragma unroll
        for (int q = 0; q < 4; q++)
            gl_lds16(gB + (size_t)q * (64 * ROWB) + gko, sb + LDSB2 + q * 8192 + sdst);
    };
    auto COMPUTE = [&](int soff) {
        const char* cb = smem + soff;
        bf16x8 bH[4], bL[4];
#pragma unroll
        for (int j = 0; j < 4; j++) {
            const int ro = bRow + j * 2048;
            bH[j] = *(const bf16x8*)(cb + ro + colH);
            bL[j] = *(const bf16x8*)(cb + ro + colL);
        }
#pragma unroll
        for (int h = 0; h < 2; h++) {
            bf16x8 aH[4], aL[4];
#pragma unroll
            for (int i = 0; i < 4; i++) {
                const int ro = aRow + h * 8192 + i * 2048;
                aH[i] = *(const bf16x8*)(cb + ro + colH);
                aL[i] = *(const bf16x8*)(cb + ro + colL);
            }
            __builtin_amdgcn_s_setprio(1);
#pragma unroll
            for (int i = 0; i < 4; i++)
#pragma unroll
                for (int j = 0; j < 4; j++)
                    acc[h * 4 + i][j] = __builtin_amdgcn_mfma_f32_16x16x32_bf16(aH[i], bH[j], acc[h * 4 + i][j], 0, 0, 0);
#pragma unroll
            for (int i = 0; i < 4; i++)
#pragma unroll
                for (int j = 0; j < 4; j++)
                    acc[h * 4 + i][j] = __builtin_amdgcn_mfma_f32_16x16x32_bf16(aH[i], bL[j], acc[h * 4 + i][j], 0, 0, 0);
#pragma unroll
            for (int i = 0; i < 4; i++)
#pragma unroll
                for (int j = 0; j < 4; j++)
                    acc[h * 4 + i][j] = __builtin_amdgcn_mfma_f32_16x16x32_bf16(aL[i], bH[j], acc[h * 4 + i][j], 0, 0, 0);
            __builtin_amdgcn_s_setprio(0);
        }
    };

    STAGE(0, 0);
    int ktn = 1;
#pragma unroll 1
    for (int it = 0; it < NKT / 2; ++it) {
        STAGE(SLOT2, ktn); ktn = (ktn + 1) & (NKT - 1);
        asm volatile("s_waitcnt vmcnt(8)" ::: "memory");
        __builtin_amdgcn_s_barrier();
        COMPUTE(0);
        asm volatile("s_waitcnt lgkmcnt(0)" ::: "memory");
        __builtin_amdgcn_s_barrier();
        STAGE(0, ktn); ktn = (ktn + 1) & (NKT - 1);
        asm volatile("s_waitcnt vmcnt(8)" ::: "memory");
        __builtin_amdgcn_s_barrier();
        COMPUTE(SLOT2);
        asm volatile("s_waitcnt lgkmcnt(0)" ::: "memory");
        __builtin_amdgcn_s_barrier();
    }
}

// ---------------------------------------------------------------------------
// M partials: Mpart[z] = Wt[M0..] @ Wt[N0..]^T over K-chunk z.  (v1)
// ---------------------------------------------------------------------------
__global__ __launch_bounds__(512, 2) void k_wtw(
        const char* __restrict__ Wt, float* __restrict__ Mpart, int nkt) {
    const int M0 = blockIdx.x * 256, N0 = blockIdx.y * 128, z = blockIdx.z;
    f32x4 acc[4][4];
    gemm_mainloop<1>(Wt + (size_t)M0 * ROWB, Wt + (size_t)N0 * ROWB, acc, z * nkt, nkt);

    const int t = threadIdx.x, lane = t & 63, w = t >> 6;
    const int l16 = lane & 15, quad = lane >> 4, mw = w >> 1, nw = w & 1;
    float* Sp = Mpart + ((size_t)z << 20)
              + (size_t)(M0 + mw * 64 + quad * 4) * 1024 + N0 + nw * 64;
#pragma unroll
    for (int i = 0; i < 4; i++)
#pragma unroll
        for (int j = 0; j < 4; j++)
#pragma unroll
            for (int r = 0; r < 4; r++)
                Sp[(size_t)(i * 16 + r) * 1024 + j * 16 + l16] = acc[i][j][r];
}

// ---------------------------------------------------------------------------
// Reduce M partials -> split-interleaved Mhl.
// ---------------------------------------------------------------------------
__global__ __launch_bounds__(256) void k_mreduce(
        const float* __restrict__ Mpart, unsigned short* __restrict__ Mhl, int zn) {
    const int i = blockIdx.x;
    const int j = threadIdx.x * 4;
    float4 s = {0.f, 0.f, 0.f, 0.f};
    for (int z = 0; z < zn; z++) {
        float4 v = *(const float4*)(Mpart + ((size_t)z << 20) + (size_t)i * 1024 + j);
        s.x += v.x; s.y += v.y; s.z += v.z; s.w += v.w;
    }
    unsigned short h0 = f2bf(s.x), h1 = f2bf(s.y), h2 = f2bf(s.z), h3 = f2bf(s.w);
    unsigned short l0 = f2bf(s.x - bf2f(h0)), l1 = f2bf(s.y - bf2f(h1));
    unsigned short l2 = f2bf(s.z - bf2f(h2)), l3 = f2bf(s.w - bf2f(h3));
    uint2 hu, lu;
    hu.x = (uint32_t)h0 | ((uint32_t)h1 << 16);
    hu.y = (uint32_t)h2 | ((uint32_t)h3 << 16);
    lu.x = (uint32_t)l0 | ((uint32_t)l1 << 16);
    lu.y = (uint32_t)l2 | ((uint32_t)l3 << 16);
    const size_t o = (size_t)i * 2048 + ((j >> 5) << 6) + (j & 31);
    *(uint2*)&Mhl[o]      = hu;
    *(uint2*)&Mhl[o + 32] = lu;
}

// ---------------------------------------------------------------------------
// c = W^T b.  Partial slabs + atomicAdd.
// ---------------------------------------------------------------------------
__global__ __launch_bounds__(256) void k_wtb(
        const float* __restrict__ W, const float* __restrict__ b,
        float* __restrict__ c) {
    const int k = blockIdx.x * 256 + threadIdx.x;
    const int n0 = blockIdx.y * 128;
    float s = 0.f;
#pragma unroll 4
    for (int n = 0; n < 128; n++) s += b[n0 + n] * W[(size_t)(n0 + n) * D_ + k];
    atomicAdd(&c[k], s);
}

// ---------------------------------------------------------------------------
// v2[r] = io[r] . c   (per-column softmax bias; exact).  One wave per row.
// ---------------------------------------------------------------------------
__global__ __launch_bounds__(256) void k_v2(
        const float* __restrict__ io, const float* __restrict__ c,
        float* __restrict__ v2) {
    __shared__ float cs[1024];
    const int t = threadIdx.x;
#pragma unroll
    for (int q = 0; q < 4; q++) cs[q * 256 + t] = c[q * 256 + t];
    __syncthreads();
    const int r = blockIdx.x * 4 + (t >> 6);
    const int lane = t & 63;
    const float* row = io + (size_t)r * D_ + lane * 16;
    float s = 0.f;
#pragma unroll
    for (int q = 0; q < 4; q++) {
        float4 v = ((const float4*)row)[q];
        s += v.x * cs[lane * 16 + q * 4 + 0] + v.y * cs[lane * 16 + q * 4 + 1]
           + v.z * cs[lane * 16 + q * 4 + 2] + v.w * cs[lane * 16 + q * 4 + 3];
    }
#pragma unroll
    for (int o = 32; o > 0; o >>= 1) s += __shfl_xor(s, o, 64);
    if (lane == 0) v2[r] = s;
}

// ---------------------------------------------------------------------------
// K1: projection GEMM (v1 256x128, 3-pass, natural map, 256 blocks).
// A = XHL, B = Mhl (symmetric).  C = x@M -> hi/lo interleaved into EHL.
// ---------------------------------------------------------------------------
__global__ __launch_bounds__(512, 2) void k_gproj(
        const char* __restrict__ Ahl, const char* __restrict__ Mhl,
        unsigned short* __restrict__ Ehl) {
    const int M0 = blockIdx.x * 256, N0 = blockIdx.y * 128;
    f32x4 acc[4][4];
    gemm_mainloop<1>(Ahl + (size_t)M0 * ROWB, Mhl + (size_t)N0 * ROWB, acc, 0, NKT);

    const int t = threadIdx.x, lane = t & 63, w = t >> 6;
    const int l16 = lane & 15, quad = lane >> 4, mw = w >> 1, nw = w & 1;
#pragma unroll
    for (int j = 0; j < 4; j++) {
        const int n = N0 + nw * 64 + j * 16 + l16;
        unsigned short* eb = Ehl + (size_t)(M0 + mw * 64 + quad * 4) * 2048
                             + (size_t)(n >> 5) * 64 + (n & 31);
#pragma unroll
        for (int i = 0; i < 4; i++)
#pragma unroll
            for (int r = 0; r < 4; r++) {
                float v = acc[i][j][r];
                unsigned short h  = f2bf(v);
                unsigned short lo = f2bf(v - bf2f(h));
                unsigned short* p = eb + (size_t)(i * 16 + r) * 2048;
                p[0]  = h;
                p[32] = lo;
            }
    }
}

// ---------------------------------------------------------------------------
// K2: S[b] = (xM)[b] @ o[b]^T + v2[col] (v2 mainloop, 3-pass, XCD remap).
// ---------------------------------------------------------------------------
__global__ __launch_bounds__(512, 2) void k_gscores(
        const char* __restrict__ Ehl, const char* __restrict__ Ohl,
        const float* __restrict__ v2, float* __restrict__ S) {
    int mb, nb_, zb;
    xcd_remap(L_ / 256, L_ / 256, mb, nb_, zb);
    const int M0 = mb * 256, N0 = nb_ * 256, bb = zb;
    const char* Ae = Ehl + (size_t)(bb * L_ + M0) * ROWB;
    const char* Be = Ohl + (size_t)(bb * L_ + N0) * ROWB;
    f32x4 acc[8][4];
    gemm_mainloop2(Ae, Be, acc);

    const int t = threadIdx.x, lane = t & 63, w = t >> 6;
    const int l16 = lane & 15, quad = lane >> 4, mw = w >> 2, nw = w & 3;
    float* Sp = S + ((size_t)bb * L_ + M0 + mw * 128 + quad * 4) * (size_t)L_
                  + N0 + nw * 64;
    const float* v2p = v2 + (size_t)bb * L_ + N0 + nw * 64;
#pragma unroll
    for (int j = 0; j < 4; j++) {
        const float vb = v2p[j * 16 + l16];
#pragma unroll
        for (int i = 0; i < 8; i++)
#pragma unroll
            for (int r = 0; r < 4; r++)
                Sp[(size_t)(i * 16 + r) * L_ + j * 16 + l16] = acc[i][j][r] + vb;
    }
}

// ---------------------------------------------------------------------------
// K3: row softmax: P[r] = bf16(exp(S[r]-max)*invSum).
// ---------------------------------------------------------------------------
__global__ __launch_bounds__(256) void k_rowsoftmax(
        const float* __restrict__ S, unsigned short* __restrict__ P) {
    const size_t r = blockIdx.x;
    const float* row = S + r * (size_t)L_;
    const int t = threadIdx.x, lane = t & 63, wave = t >> 6;
    float4 v0 = ((const float4*)row)[t];
    float4 v1 = ((const float4*)row)[t + 256];
    float mx = fmaxf(fmaxf(fmaxf(v0.x, v0.y), fmaxf(v0.z, v0.w)),
                     fmaxf(fmaxf(v1.x, v1.y), fmaxf(v1.z, v1.w)));
#pragma unroll
    for (int o = 32; o > 0; o >>= 1) mx = fmaxf(mx, __shfl_xor(mx, o, 64));
    __shared__ float red[4];
    __shared__ float bmax, binv;
    if (lane == 0) red[wave] = mx;
    __syncthreads();
    if (t == 0) bmax = fmaxf(fmaxf(red[0], red[1]), fmaxf(red[2], red[3]));
    __syncthreads();
    const float m = bmax;
    float e0x = __expf(fminf(v0.x - m, 0.f)), e0y = __expf(fminf(v0.y - m, 0.f));
    float e0z = __expf(fminf(v0.z - m, 0.f)), e0w = __expf(fminf(v0.w - m, 0.f));
    float e1x = __expf(fminf(v1.x - m, 0.f)), e1y = __expf(fminf(v1.y - m, 0.f));
    float e1z = __expf(fminf(v1.z - m, 0.f)), e1w = __expf(fminf(v1.w - m, 0.f));
    float s = e0x + e0y + e0z + e0w + e1x + e1y + e1z + e1w;
#pragma unroll
    for (int o = 32; o > 0; o >>= 1) s += __shfl_xor(s, o, 64);
    __syncthreads();
    if (lane == 0) red[wave] = s;
    __syncthreads();
    if (t == 0) binv = 1.0f / (red[0] + red[1] + red[2] + red[3]);
    __syncthreads();
    const float ril = binv;
    uint2 a, b;
    a.x = (uint32_t)f2bf(e0x * ril) | ((uint32_t)f2bf(e0y * ril) << 16);
    a.y = (uint32_t)f2bf(e0z * ril) | ((uint32_t)f2bf(e0w * ril) << 16);
    b.x = (uint32_t)f2bf(e1x * ril) | ((uint32_t)f2bf(e1y * ril) << 16);
    b.y = (uint32_t)f2bf(e1z * ril) | ((uint32_t)f2bf(e1w * ril) << 16);
    uint2* pr = (uint2*)(P + r * (size_t)L_);
    pr[t]       = a;
    pr[t + 256] = b;
}

// ---------------------------------------------------------------------------
// K4: out[b] = P[b] @ Vt[b]^T (v1 single-pass, XCD remap, 256 blocks).
// ---------------------------------------------------------------------------
__global__ __launch_bounds__(512, 2) void k_pvg(
        const char* __restrict__ Pbf, const char* __restrict__ Vt,
        float* __restrict__ out) {
    int mb, nb_, zb;
    xcd_remap(L_ / 256, D_ / 128, mb, nb_, zb);
    const int M0 = mb * 256, N0 = nb_ * 128, bb = zb;
    const char* Ae = Pbf + ((size_t)bb * L_ + M0) * ROWB;
    const char* Be = Vt + ((size_t)bb * D_ + N0) * ROWB;
    f32x4 acc[4][4];
    gemm_mainloop<0>(Ae, Be, acc, 0, NKT);

    const int t = threadIdx.x, lane = t & 63, w = t >> 6;
    const int l16 = lane & 15, quad = lane >> 4, mw = w >> 1, nw = w & 1;
    float* op = out + ((size_t)bb * L_ + M0 + mw * 64 + quad * 4) * (size_t)D_
                    + N0 + nw * 64;
#pragma unroll
    for (int i = 0; i < 4; i++)
#pragma unroll
        for (int j = 0; j < 4; j++)
#pragma unroll
            for (int r = 0; r < 4; r++)
                op[(size_t)(i * 16 + r) * D_ + j * 16 + l16] = acc[i][j][r];
}

// ---------------------------------------------------------------------------
extern "C" void kernel_launch(void* const* d_in, const int* in_sizes, int n_in,
                              void* d_out, int out_size, void* d_ws, size_t ws_size,
                              hipStream_t stream) {
    const float* ix   = (const float*)d_in[0];
    const float* io   = (const float*)d_in[1];
    const float* W    = (const float*)d_in[2];
    const float* bias = (const float*)d_in[3];
    float* out = (float*)d_out;

    hipFuncSetAttribute((const void*)k_gproj,
                        hipFuncAttributeMaxDynamicSharedMemorySize, DYN_LDS);
    hipFuncSetAttribute((const void*)k_gscores,
                        hipFuncAttributeMaxDynamicSharedMemorySize, DYN_LDS2);
    hipFuncSetAttribute((const void*)k_wtw,
                        hipFuncAttributeMaxDynamicSharedMemorySize, DYN_LDS);
    hipFuncSetAttribute((const void*)k_pvg,
                        hipFuncAttributeMaxDynamicSharedMemorySize, DYN_LDS);

    const size_t MB = 1024 * 1024;
    const size_t PB_EI = (size_t)L_ * ROWB;      // 8 MiB: interleaved split per batch
    const size_t PB_S  = (size_t)L_ * L_ * 4;    // 16 MiB
    const size_t PB_E  = (size_t)L_ * D_ * 2;    // 4 MiB (Vt bf16)
    const size_t PB_ST = (size_t)L_ * 4;         // 8 KiB

    int nb = 8;
    while (nb > 1) {
        size_t need = 4 * MB + (size_t)nb * (2 * PB_EI + PB_S + PB_E + 2 * PB_ST) + 8192;
        if (need <= ws_size) break;
        nb >>= 1;
    }

    char* ws = (char*)d_ws;
    size_t off = 0;
    unsigned short* Mhl = (unsigned short*)(ws + off); off += 4 * MB;
    unsigned short* EHL = (unsigned short*)(ws + off); off += (size_t)nb * PB_EI;
    unsigned short* OHL = (unsigned short*)(ws + off); off += (size_t)nb * PB_EI;
    char* regA = ws + off;                             off += (size_t)nb * PB_S;
    unsigned short* Vt = (unsigned short*)(ws + off);  off += (size_t)nb * PB_E;
    float* v2   = (float*)(ws + off);                  off += (size_t)nb * PB_ST;
    float* cvec = (float*)(ws + off);                  off += 4096;
    unsigned short* WtHL = EHL;
    float* Mpart = (float*)OHL;
    unsigned short* Pbf = EHL;
    const int zsplit = (nb >= 2) ? 8 : 4;
    const int nktc = NKT / zsplit;

    // ---- M = W^T W (once) + c = W^T b ----
    k_tsplit<<<dim3(16, 16), 256, 0, stream>>>(W, WtHL);
    k_wtw<<<dim3(4, 8, zsplit), 512, DYN_LDS, stream>>>((const char*)WtHL, Mpart, nktc);
    k_mreduce<<<1024, 256, 0, stream>>>(Mpart, Mhl, zsplit);
    hipMemsetAsync(cvec, 0, D_ * sizeof(float), stream);
    k_wtb<<<dim3(4, 8), 256, 0, stream>>>(W, bias, cvec);

    for (int b0 = 0; b0 < 8; b0 += nb) {
        const float* ixc = ix + (size_t)b0 * L_ * D_;
        const float* ioc = io + (size_t)b0 * L_ * D_;
        float* outc = out + (size_t)b0 * L_ * D_;
        const int nLD4 = nb * L_ * D_ / 4;
        const int nbL = nb * L_;
        float* S = (float*)regA;

        k_split<<<nb * 2048, 256, 0, stream>>>(ixc, (unsigned short*)regA, nLD4);
        k_split<<<nb * 2048, 256, 0, stream>>>(ioc, OHL, nLD4);
        k_transpose<<<dim3(32, 16, nb), 256, 0, stream>>>(ioc, Vt);
        k_v2<<<nbL / 4, 256, 0, stream>>>(ioc, cvec, v2);
        k_gproj<<<dim3(nbL / 256, D_ / 128), 512, DYN_LDS, stream>>>(
            (const char*)regA, (const char*)Mhl, EHL);
        k_gscores<<<dim3(L_ / 256, L_ / 256, nb), 512, DYN_LDS2, stream>>>(
            (const char*)EHL, (const char*)OHL, v2, S);
        k_rowsoftmax<<<2048 * nb, 256, 0, stream>>>(S, Pbf);
        k_pvg<<<dim3(L_ / 256, D_ / 128, nb), 512, DYN_LDS, stream>>>(
            (const char*)Pbf, (const char*)Vt, outc);
    }
}